// Round 12
// baseline (123.309 us; speedup 1.0000x reference)
//
#include <hip/hip_runtime.h>
#include <hip/hip_bf16.h>
#include <math.h>

#define D 128
#define NT 3
#define KTOT (D * (NT + 1))   // 512
#define TM 32                 // nodes per fused block
#define TCAP 12               // per-(node,type) csr capacity
#define NCAP (3 * TCAP)       // 36 slots per node

typedef __attribute__((ext_vector_type(8))) __bf16 bf16x8;
typedef __attribute__((ext_vector_type(4))) float f32x4;

__device__ inline unsigned short f2bf(float f) {
    unsigned int u = __float_as_uint(f);
    unsigned int r = (u + 0x7FFFu + ((u >> 16) & 1u)) >> 16;
    return (unsigned short)r;
}
__device__ inline float bf2f(unsigned int low16) {
    return __uint_as_float(low16 << 16);
}

// ---------------- zero helper (fallback path) ----------------
__global__ void zero_kernel(float* __restrict__ p, long long n4) {
    long long i = (long long)blockIdx.x * blockDim.x + threadIdx.x;
    long long stride = (long long)gridDim.x * blockDim.x;
    float4 z = make_float4(0.f, 0.f, 0.f, 0.f);
    for (; i < n4; i += stride) ((float4*)p)[i] = z;
}

// ---------------- prep: softmax(attention) -> wcat, biasb, bfrag; zero deg4/ovfc ----------------
__global__ void prep_kernel(const float* __restrict__ W_edge, const float* __restrict__ b_edge,
                            const float* __restrict__ W_self, const float* __restrict__ b_self,
                            const float* __restrict__ attention,
                            float* __restrict__ wcat, float* __restrict__ biasb,
                            unsigned short* __restrict__ bfrag,
                            int* __restrict__ zeroMe, int zeroN) {
    float a0 = attention[0], a1 = attention[1], a2 = attention[2], a3 = attention[3];
    float m = fmaxf(fmaxf(a0, a1), fmaxf(a2, a3));
    float e0 = expf(a0 - m), e1 = expf(a1 - m), e2 = expf(a2 - m), e3 = expf(a3 - m);
    float inv = 1.f / (e0 + e1 + e2 + e3);
    float at[4] = {e0 * inv, e1 * inv, e2 * inv, e3 * inv};

    int idx0 = blockIdx.x * blockDim.x + threadIdx.x;
    int stride = gridDim.x * blockDim.x;
    if (zeroMe) {
        for (int i = idx0; i < zeroN; i += stride) zeroMe[i] = 0;
    }
    for (int i = idx0; i < KTOT * D; i += stride) {
        int k = i >> 7, j = i & (D - 1);
        float v;
        if (k < D) {
            v = at[NT] * W_self[k * D + j];
        } else {
            int t = (k - D) >> 7;
            int kk = (k - D) & (D - 1);
            v = at[t] * W_edge[(t * D + kk) * D + j];
        }
        wcat[i] = v;
    }
    for (int i = idx0; i < KTOT; i += stride) {
        if (i < NT * D) {
            int t = i >> 7, j = i & (D - 1);
            biasb[i] = at[t] * b_edge[t * D + j];
        } else {
            biasb[i] = at[NT] * b_self[i - NT * D];
        }
    }
    if (bfrag) {
        // bfrag: [(step*8+cf)*64+lane]*8 ; B[k][col], col=cf*16+(l&15), k=step*32+(l>>4)*8+j
        for (int i = idx0; i < 16 * 8 * 64; i += stride) {
            int l = i & 63;
            int cf = (i >> 6) & 7;
            int step = i >> 9;
            int col = cf * 16 + (l & 15);
            int kb = step * 32 + ((l >> 4) * 8);
#pragma unroll
            for (int j = 0; j < 8; ++j) {
                int k = kb + j;
                float v;
                if (k < D) {
                    v = at[NT] * W_self[k * D + col];
                } else {
                    int t = (k - D) >> 7;
                    int kk = (k - D) & (D - 1);
                    v = at[t] * W_edge[(t * D + kk) * D + col];
                }
                bfrag[(size_t)i * 8 + j] = f2bf(v);
            }
        }
    }
}

// ---------------- merged per-thread: 1 edge fill (type-segmented csr) + grid-strided x->bf16 ----------------
__global__ __launch_bounds__(256) void xcvt_fill_kernel(
    const float* __restrict__ x, unsigned short* __restrict__ xb, int nN,
    const int* __restrict__ ei, const int* __restrict__ et, const float* __restrict__ ew,
    int* __restrict__ deg4, int2* __restrict__ csr, int* __restrict__ ovfcnt,
    int* __restrict__ ovflist, int nE) {
    int e = blockIdx.x * blockDim.x + threadIdx.x;

    // issue edge loads early
    int dst = 0, src = 0, t = 0;
    float w = 0.f;
    bool act = (e < nE);
    if (act) {
        dst = ei[nE + e];
        src = ei[e];
        t = et[e];
        w = ew[e];
    }

    // streaming xcvt (hides edge-load latency)
    int total = nN * (D / 4);
    int stride = gridDim.x * blockDim.x;
    for (int i = e; i < total; i += stride) {
        int n = i >> 5;
        int c4 = (i & 31) * 4;
        float4 v = *(const float4*)(x + (size_t)n * D + c4);
        ushort4 o;
        o.x = f2bf(v.x); o.y = f2bf(v.y); o.z = f2bf(v.z); o.w = f2bf(v.w);
        *(ushort4*)(xb + (size_t)n * D + c4) = o;
    }

    // edge bucketing into per-type segment
    if (act) {
        int pos = atomicAdd(deg4 + (size_t)dst * 4 + t, 1);
        if (pos < TCAP) {
            csr[(size_t)dst * NCAP + t * TCAP + pos] = make_int2(src, __float_as_int(w));
        } else {
            int o = atomicAdd(ovfcnt, 1);
            ovflist[o] = e;
        }
    }
}

// ---------------- fused gather + MFMA GEMM (type-segmented gather, barrier-free GEMM) ----------------
// Block: 32 nodes, 512 threads (8 waves). LDS: A[32][64 chunks of 16B] (chunk XOR swizzle) @0
// (32KB); s[32][3] f32 @32768. Total 33152 -> 4 blocks/CU (32 waves/CU).
__global__ __launch_bounds__(512, 8) void fused_gemm_kernel(
    const unsigned short* __restrict__ xb, const int2* __restrict__ csr,
    const int* __restrict__ deg4, const unsigned short* __restrict__ bfrag,
    const float* __restrict__ biasb,
    const int* __restrict__ ei, const int* __restrict__ et, const float* __restrict__ ew,
    const int* __restrict__ ovfc, const int* __restrict__ ovfl,
    float* __restrict__ out, int nN, int nE) {
    __shared__ unsigned char lds[33152];
    float* sL = (float*)(lds + 32768);
    int t = threadIdx.x;
    int w = t >> 6;
    int lane = t & 63;
    int gl = lane & 15;
    int gbase = lane & 48;
    int row0 = blockIdx.x * TM;

    // ---------- gather phase: wave w owns nodes row0 + w*4 .. +3 (16 lanes/node) ----------
    int lrow = w * 4 + (lane >> 4);
    int node = row0 + lrow;
    int nclamp = (node < nN) ? node : (nN - 1);
    int swz = lrow & 15;
    int4 dgv = make_int4(0, 0, 0, 0);
    if (node < nN) dgv = *(const int4*)(deg4 + (size_t)nclamp * 4);
    int cnt0 = dgv.x > TCAP ? TCAP : dgv.x;
    int cnt1 = dgv.y > TCAP ? TCAP : dgv.y;
    int cnt2 = dgv.z > TCAP ? TCAP : dgv.z;

    const int2* c = csr + (size_t)nclamp * NCAP;
    int gli = (gl < TCAP) ? gl : (TCAP - 1);
    int2 m0 = c[gli];
    int2 m1 = c[TCAP + gli];
    int2 m2 = c[2 * TCAP + gli];

    // own x row -> LDS (chunk-XOR swizzled, both sides — rule #21)
    {
        uint4 xo = *(const uint4*)(xb + (size_t)nclamp * D + gl * 8);
        *(uint4*)(lds + lrow * 1024 + ((gl ^ swz) << 4)) = xo;
    }

    float sw0 = 0.f, sw1 = 0.f, sw2 = 0.f;

#define ACCP(uA, uB, jj0, jj1)                                                      \
    aacc[jj0] = fmaf(wA, __uint_as_float((uA) << 16), aacc[jj0]);                   \
    aacc[jj1] = fmaf(wA, __uint_as_float((uA) & 0xFFFF0000u), aacc[jj1]);           \
    aacc[jj0] = fmaf(wB, __uint_as_float((uB) << 16), aacc[jj0]);                   \
    aacc[jj1] = fmaf(wB, __uint_as_float((uB) & 0xFFFF0000u), aacc[jj1]);

#define TYPELOOP(mt, cntt, swt, tt) do {                                            \
    float aacc[8];                                                                  \
    _Pragma("unroll") for (int j = 0; j < 8; ++j) aacc[j] = 0.f;                    \
    for (int i = 0; i < cntt; i += 2) {                                             \
        int exA = __shfl(mt.x, gbase + i);                                          \
        int ewA = __shfl(mt.y, gbase + i);                                          \
        int exB = __shfl(mt.x, gbase + i + 1);                                      \
        int ewB = __shfl(mt.y, gbase + i + 1);                                      \
        bool actB = (i + 1 < cntt);                                                 \
        int srcA = exA; if ((unsigned)srcA >= (unsigned)nN) srcA = 0;               \
        int srcB = actB ? exB : 0; if ((unsigned)srcB >= (unsigned)nN) srcB = 0;    \
        float wA = __int_as_float(ewA);                                             \
        float wB = actB ? __int_as_float(ewB) : 0.f;                                \
        uint4 xa = *(const uint4*)(xb + (size_t)srcA * D + gl * 8);                 \
        uint4 xv = *(const uint4*)(xb + (size_t)srcB * D + gl * 8);                 \
        swt += wA + wB;                                                             \
        ACCP(xa.x, xv.x, 0, 1) ACCP(xa.y, xv.y, 2, 3)                               \
        ACCP(xa.z, xv.z, 4, 5) ACCP(xa.w, xv.w, 6, 7)                               \
    }                                                                               \
    uint4 o;                                                                        \
    o.x = (unsigned)f2bf(aacc[0]) | ((unsigned)f2bf(aacc[1]) << 16);                \
    o.y = (unsigned)f2bf(aacc[2]) | ((unsigned)f2bf(aacc[3]) << 16);                \
    o.z = (unsigned)f2bf(aacc[4]) | ((unsigned)f2bf(aacc[5]) << 16);                \
    o.w = (unsigned)f2bf(aacc[6]) | ((unsigned)f2bf(aacc[7]) << 16);                \
    *(uint4*)(lds + lrow * 1024 + 256 + (tt) * 256 + ((gl ^ swz) << 4)) = o;        \
} while (0)

    TYPELOOP(m0, cnt0, sw0, 0);
    TYPELOOP(m1, cnt1, sw1, 1);
    TYPELOOP(m2, cnt2, sw2, 2);
#undef TYPELOOP
#undef ACCP

    if (gl < 3) {
        float sv = (gl == 0) ? sw0 : ((gl == 1) ? sw1 : sw2);
        sL[lrow * NT + gl] = sv;
    }
    __syncthreads();

    // ---------- overflow patch (cnt == 0 in practice; correct for any data) ----------
    int cnt = *ovfc;
    if (cnt > 0) {
        if (w == 0 && lane < 16) {
            for (int i = 0; i < cnt; ++i) {
                int e = ovfl[i];
                int dst = ei[nE + e];
                if (dst >= row0 && dst < row0 + TM && dst < nN) {
                    int tt = et[e];
                    float wt = ew[e];
                    int src = ei[e];
                    int lr = dst - row0;
                    uint4* p = (uint4*)(lds + lr * 1024 + 256 + tt * 256 + ((lane ^ (lr & 15)) << 4));
                    uint4 cu = *p;
                    uint4 xr = *(const uint4*)(xb + (size_t)src * D + lane * 8);
                    float f0 = bf2f(cu.x & 0xFFFF) + wt * bf2f(xr.x & 0xFFFF);
                    float f1 = bf2f(cu.x >> 16)    + wt * bf2f(xr.x >> 16);
                    float f2 = bf2f(cu.y & 0xFFFF) + wt * bf2f(xr.y & 0xFFFF);
                    float f3 = bf2f(cu.y >> 16)    + wt * bf2f(xr.y >> 16);
                    float f4 = bf2f(cu.z & 0xFFFF) + wt * bf2f(xr.z & 0xFFFF);
                    float f5 = bf2f(cu.z >> 16)    + wt * bf2f(xr.z >> 16);
                    float f6 = bf2f(cu.w & 0xFFFF) + wt * bf2f(xr.w & 0xFFFF);
                    float f7 = bf2f(cu.w >> 16)    + wt * bf2f(xr.w >> 16);
                    cu.x = (unsigned int)f2bf(f0) | ((unsigned int)f2bf(f1) << 16);
                    cu.y = (unsigned int)f2bf(f2) | ((unsigned int)f2bf(f3) << 16);
                    cu.z = (unsigned int)f2bf(f4) | ((unsigned int)f2bf(f5) << 16);
                    cu.w = (unsigned int)f2bf(f6) | ((unsigned int)f2bf(f7) << 16);
                    *p = cu;
                    if (lane == 0) sL[lr * NT + tt] += wt;
                }
            }
        }
        __syncthreads();
    }

    // ---------- GEMM phase: 16 K-steps, wave w -> cols w*16..+15, NO barriers ----------
    int ll = lane & 15;
    int ck = lane >> 4;
    f32x4 acc0 = (f32x4){0.f, 0.f, 0.f, 0.f};
    f32x4 acc1 = (f32x4){0.f, 0.f, 0.f, 0.f};
#pragma unroll 4
    for (int st = 0; st < 16; ++st) {
        bf16x8 b = *(const bf16x8*)(bfrag + (size_t)st * 4096 + w * 512 + lane * 8);
        int cc = st * 4 + ck;
        int phys = (cc & 48) | ((cc & 15) ^ ll);
        bf16x8 a0 = *(const bf16x8*)(lds + ll * 1024 + (phys << 4));
        bf16x8 a1 = *(const bf16x8*)(lds + (16 + ll) * 1024 + (phys << 4));
        acc0 = __builtin_amdgcn_mfma_f32_16x16x32_bf16(a0, b, acc0, 0, 0, 0);
        acc1 = __builtin_amdgcn_mfma_f32_16x16x32_bf16(a1, b, acc1, 0, 0, 0);
    }

    // ---------- epilogue ----------
    int colb = w * 16 + ll;
    float bb0 = biasb[colb], bb1 = biasb[D + colb], bb2 = biasb[2 * D + colb], bs4 = biasb[3 * D + colb];
    const float kInvSqrt2 = 0.70710678118654752440f;
#pragma unroll
    for (int fr = 0; fr < 2; ++fr) {
        f32x4 A = fr ? acc1 : acc0;
#pragma unroll
        for (int reg = 0; reg < 4; ++reg) {
            int lr = fr * 16 + ck * 4 + reg;
            long row = (long)row0 + lr;
            if (row >= nN) continue;
            float s0 = sL[lr * NT + 0];
            float s1 = sL[lr * NT + 1];
            float s2 = sL[lr * NT + 2];
            float v = A[reg] + bs4 + s0 * bb0 + s1 * bb1 + s2 * bb2;
            v = 0.5f * v * (1.f + erff(v * kInvSqrt2));
            out[row * D + colb] = v;
        }
    }
}

// ================= FALLBACK PATH (small ws): f32 atomic scatter + f32 GEMM =================
__global__ __launch_bounds__(256) void scatterA_kernel(
    const float* __restrict__ x, const int* __restrict__ ei,
    const int* __restrict__ et, const float* __restrict__ ew,
    float* __restrict__ agg, float* __restrict__ s, int nE) {
    int gtid = blockIdx.x * blockDim.x + threadIdx.x;
    int wave = gtid >> 6;
    int lane = threadIdx.x & 63;
    int nw = (gridDim.x * blockDim.x) >> 6;
    for (int e = wave; e < nE; e += nw) {
        int src = ei[e];
        int dst = ei[nE + e];
        int t = et[e];
        float w = ew[e];
        float2 xv = *(const float2*)(x + (size_t)src * D + lane * 2);
        float* p = agg + (size_t)dst * (NT * D) + t * D + lane * 2;
        unsafeAtomicAdd(p, w * xv.x);
        unsafeAtomicAdd(p + 1, w * xv.y);
        if (lane == 0) unsafeAtomicAdd(s + (size_t)dst * NT + t, w);
    }
}

#define BM 64
#define BK 32
__global__ __launch_bounds__(256) void gemm_gelu_kernel(
    const float* __restrict__ x, const float* __restrict__ agg,
    const float* __restrict__ s, const float* __restrict__ wcat,
    const float* __restrict__ biasb, float* __restrict__ out, int nNodes) {
    __shared__ float As[BK][BM + 1];
    __shared__ float Bs[BK][D];

    int tx = threadIdx.x;
    int row0 = blockIdx.x * BM;
    int cg = tx & 31;
    int rg = tx >> 5;
    int lr = tx >> 3;
    int lc = (tx & 7) * 4;

    float acc[8][4];
#pragma unroll
    for (int i = 0; i < 8; ++i)
#pragma unroll
        for (int j = 0; j < 4; ++j) acc[i][j] = 0.f;

    for (int k0 = 0; k0 < KTOT; k0 += BK) {
        const float* srcBase;
        int strideA, koff;
        if (k0 < D) { srcBase = x; strideA = D; koff = k0; }
        else        { srcBase = agg; strideA = NT * D; koff = k0 - D; }
#pragma unroll
        for (int h = 0; h < 2; ++h) {
            int r = lr + h * 32;
            int node = row0 + r;
            if (node >= nNodes) node = nNodes - 1;
            float4 v = *(const float4*)(srcBase + (size_t)node * strideA + koff + lc);
            As[lc + 0][r] = v.x; As[lc + 1][r] = v.y;
            As[lc + 2][r] = v.z; As[lc + 3][r] = v.w;
        }
        {
            int br = tx >> 5;
            int bc = (tx & 31) * 4;
#pragma unroll
            for (int h = 0; h < 4; ++h) {
                int r = br + h * 8;
                *(float4*)(&Bs[r][bc]) = *(const float4*)(wcat + (size_t)(k0 + r) * D + bc);
            }
        }
        __syncthreads();
#pragma unroll
        for (int kk = 0; kk < BK; ++kk) {
            float4 b = *(const float4*)(&Bs[kk][cg * 4]);
            float a[8];
            *(float4*)(a)     = *(const float4*)(&As[kk][rg * 8]);
            *(float4*)(a + 4) = *(const float4*)(&As[kk][rg * 8 + 4]);
#pragma unroll
            for (int i = 0; i < 8; ++i) {
                acc[i][0] = fmaf(a[i], b.x, acc[i][0]);
                acc[i][1] = fmaf(a[i], b.y, acc[i][1]);
                acc[i][2] = fmaf(a[i], b.z, acc[i][2]);
                acc[i][3] = fmaf(a[i], b.w, acc[i][3]);
            }
        }
        __syncthreads();
    }

    int jc = cg * 4;
    float4 bb0 = *(const float4*)(biasb + 0 * D + jc);
    float4 bb1 = *(const float4*)(biasb + 1 * D + jc);
    float4 bb2 = *(const float4*)(biasb + 2 * D + jc);
    float4 bsv = *(const float4*)(biasb + NT * D + jc);
#pragma unroll
    for (int i = 0; i < 8; ++i) {
        int node = row0 + rg * 8 + i;
        if (node >= nNodes) break;
        float s0 = s[(size_t)node * NT + 0];
        float s1 = s[(size_t)node * NT + 1];
        float s2 = s[(size_t)node * NT + 2];
        float4 r;
        r.x = acc[i][0] + bsv.x + s0 * bb0.x + s1 * bb1.x + s2 * bb2.x;
        r.y = acc[i][1] + bsv.y + s0 * bb0.y + s1 * bb1.y + s2 * bb2.y;
        r.z = acc[i][2] + bsv.z + s0 * bb0.z + s1 * bb1.z + s2 * bb2.z;
        r.w = acc[i][3] + bsv.w + s0 * bb0.w + s1 * bb1.w + s2 * bb2.w;
        const float kInvSqrt2 = 0.70710678118654752440f;
        r.x = 0.5f * r.x * (1.f + erff(r.x * kInvSqrt2));
        r.y = 0.5f * r.y * (1.f + erff(r.y * kInvSqrt2));
        r.z = 0.5f * r.z * (1.f + erff(r.z * kInvSqrt2));
        r.w = 0.5f * r.w * (1.f + erff(r.w * kInvSqrt2));
        *(float4*)(out + (size_t)node * D + jc) = r;
    }
}

// ================= PATH C: zero-workspace fallback =================
__global__ __launch_bounds__(256) void selfmv_kernel(
    const float* __restrict__ x, const float* __restrict__ Ws,
    const float* __restrict__ bs, const float* __restrict__ attn,
    float* __restrict__ out, int nN) {
    float a0 = attn[0], a1 = attn[1], a2 = attn[2], a3 = attn[3];
    float m = fmaxf(fmaxf(a0, a1), fmaxf(a2, a3));
    float e3 = expf(a3 - m);
    float inv = 1.f / (expf(a0 - m) + expf(a1 - m) + expf(a2 - m) + e3);
    float at3 = e3 * inv;
    int wave = (blockIdx.x * blockDim.x + threadIdx.x) >> 6;
    int lane = threadIdx.x & 63;
    int nw = (gridDim.x * blockDim.x) >> 6;
    for (int n = wave; n < nN; n += nw) {
        float2 xr = *(const float2*)(x + (size_t)n * D + lane * 2);
        float acc0 = 0.f, acc1 = 0.f;
#pragma unroll
        for (int k = 0; k < D; ++k) {
            float xv = __shfl((k & 1) ? xr.y : xr.x, k >> 1);
            float2 wv = *(const float2*)(Ws + (size_t)k * D + lane * 2);
            acc0 = fmaf(xv, wv.x, acc0);
            acc1 = fmaf(xv, wv.y, acc1);
        }
        float2 r;
        r.x = at3 * (acc0 + bs[lane * 2]);
        r.y = at3 * (acc1 + bs[lane * 2 + 1]);
        *(float2*)(out + (size_t)n * D + lane * 2) = r;
    }
}

__global__ __launch_bounds__(256) void edgemv_kernel(
    const float* __restrict__ x, const int* __restrict__ ei,
    const int* __restrict__ et, const float* __restrict__ ew,
    const float* __restrict__ We, const float* __restrict__ be,
    const float* __restrict__ attn, float* __restrict__ out, int nE) {
    float a0 = attn[0], a1 = attn[1], a2 = attn[2], a3 = attn[3];
    float m = fmaxf(fmaxf(a0, a1), fmaxf(a2, a3));
    float e0 = expf(a0 - m), e1 = expf(a1 - m), e2 = expf(a2 - m), e3 = expf(a3 - m);
    float inv = 1.f / (e0 + e1 + e2 + e3);
    float at[NT] = {e0 * inv, e1 * inv, e2 * inv};
    int wave = (blockIdx.x * blockDim.x + threadIdx.x) >> 6;
    int lane = threadIdx.x & 63;
    int nw = (gridDim.x * blockDim.x) >> 6;
    for (int e = wave; e < nE; e += nw) {
        int src = ei[e];
        int dst = ei[nE + e];
        int t = et[e];
        float sc = ew[e] * at[t];
        const float* W = We + (size_t)t * D * D;
        float2 xr = *(const float2*)(x + (size_t)src * D + lane * 2);
        float acc0 = 0.f, acc1 = 0.f;
#pragma unroll
        for (int k = 0; k < D; ++k) {
            float xv = __shfl((k & 1) ? xr.y : xr.x, k >> 1);
            float2 wv = *(const float2*)(W + (size_t)k * D + lane * 2);
            acc0 = fmaf(xv, wv.x, acc0);
            acc1 = fmaf(xv, wv.y, acc1);
        }
        float* p = out + (size_t)dst * D + lane * 2;
        unsafeAtomicAdd(p,     sc * (acc0 + be[(size_t)t * D + lane * 2]));
        unsafeAtomicAdd(p + 1, sc * (acc1 + be[(size_t)t * D + lane * 2 + 1]));
    }
}

__global__ void gelu_kernel(float* __restrict__ p, long long n4) {
    long long i = (long long)blockIdx.x * blockDim.x + threadIdx.x;
    long long stride = (long long)gridDim.x * blockDim.x;
    const float kInvSqrt2 = 0.70710678118654752440f;
    for (; i < n4; i += stride) {
        float4 r = ((float4*)p)[i];
        r.x = 0.5f * r.x * (1.f + erff(r.x * kInvSqrt2));
        r.y = 0.5f * r.y * (1.f + erff(r.y * kInvSqrt2));
        r.z = 0.5f * r.z * (1.f + erff(r.z * kInvSqrt2));
        r.w = 0.5f * r.w * (1.f + erff(r.w * kInvSqrt2));
        ((float4*)p)[i] = r;
    }
}

extern "C" void kernel_launch(void* const* d_in, const int* in_sizes, int n_in,
                              void* d_out, int out_size, void* d_ws, size_t ws_size,
                              hipStream_t stream) {
    const float* x = (const float*)d_in[0];
    const int* ei = (const int*)d_in[1];      // int64 in reference -> int32 here
    const int* et = (const int*)d_in[2];
    const float* ew = (const float*)d_in[3];
    const float* W_edge = (const float*)d_in[4];
    const float* b_edge = (const float*)d_in[5];
    const float* W_self = (const float*)d_in[6];
    const float* b_self = (const float*)d_in[7];
    const float* attention = (const float*)d_in[8];
    float* out = (float*)d_out;

    const int nN = in_sizes[0] / D;   // 100000
    const int nE = in_sizes[2];       // 600000

    // ---- fused path workspace (16B-aligned sections) ----
    size_t off = 0;
    auto take = [&](size_t bytes) { size_t o = (off + 15) & ~(size_t)15; off = o + bytes; return o; };
    size_t o_wcat  = take((size_t)KTOT * D * 4);
    size_t o_biasb = take((size_t)KTOT * 4);
    size_t o_bfrag = take(131072);
    size_t o_deg   = take(((size_t)nN * 4 + 2) * 4);      // deg4[nN*4] + ovfc
    size_t o_ovfl  = take((size_t)nE * 4);
    size_t o_csr   = take((size_t)nN * NCAP * 8);
    size_t o_xb    = take((size_t)nN * D * 2);
    size_t needFused = off;

    if (ws_size >= needFused && nN < (1 << 20)) {
        char* ws = (char*)d_ws;
        float* wcat = (float*)(ws + o_wcat);
        float* biasb = (float*)(ws + o_biasb);
        unsigned short* bfrag = (unsigned short*)(ws + o_bfrag);
        int* deg4 = (int*)(ws + o_deg);
        int* ovfc = deg4 + (size_t)nN * 4;
        int* ovfl = (int*)(ws + o_ovfl);
        int2* csr = (int2*)(ws + o_csr);
        unsigned short* xb = (unsigned short*)(ws + o_xb);

        hipLaunchKernelGGL(prep_kernel, dim3(64), dim3(256), 0, stream,
                           W_edge, b_edge, W_self, b_self, attention, wcat, biasb, bfrag,
                           deg4, nN * 4 + 2);
        hipLaunchKernelGGL(xcvt_fill_kernel, dim3((nE + 255) / 256), dim3(256), 0, stream,
                           x, xb, nN, ei, et, ew, deg4, csr, ovfc, ovfl, nE);
        hipLaunchKernelGGL(fused_gemm_kernel, dim3((nN + TM - 1) / TM), dim3(512), 0, stream,
                           xb, csr, deg4, bfrag, biasb, ei, et, ew, ovfc, ovfl, out, nN, nE);
        return;
    }

    const size_t baseFloats = (size_t)nN * NT * D + (size_t)nN * NT + (size_t)KTOT * D + KTOT;
    if (ws_size >= baseFloats * 4) {
        float* agg = (float*)d_ws;
        float* sW = agg + (size_t)nN * NT * D;
        float* wcat = sW + (size_t)nN * NT;
        float* biasb = wcat + (size_t)KTOT * D;
        long long zeroFloats = (long long)nN * (NT * D + NT);
        hipLaunchKernelGGL(zero_kernel, dim3(2048), dim3(256), 0, stream, agg, (zeroFloats + 3) / 4);
        hipLaunchKernelGGL(prep_kernel, dim3(64), dim3(256), 0, stream,
                           W_edge, b_edge, W_self, b_self, attention, wcat, biasb,
                           (unsigned short*)nullptr, (int*)nullptr, 0);
        hipLaunchKernelGGL(scatterA_kernel, dim3(2048), dim3(256), 0, stream,
                           x, ei, et, ew, agg, sW, nE);
        hipLaunchKernelGGL(gemm_gelu_kernel, dim3((nN + BM - 1) / BM), dim3(256), 0, stream,
                           x, agg, sW, wcat, biasb, out, nN);
    } else {
        hipLaunchKernelGGL(selfmv_kernel, dim3(2048), dim3(256), 0, stream,
                           x, W_self, b_self, attention, out, nN);
        hipLaunchKernelGGL(edgemv_kernel, dim3(2048), dim3(256), 0, stream,
                           x, ei, et, ew, W_edge, b_edge, attention, out, nE);
        hipLaunchKernelGGL(gelu_kernel, dim3(2048), dim3(256), 0, stream,
                           out, (long long)nN * D / 4);
    }
}

// Round 13
// 120.246 us; speedup vs baseline: 1.0255x; 1.0255x over previous
//
#include <hip/hip_runtime.h>
#include <hip/hip_bf16.h>
#include <math.h>

#define D 128
#define NT 3
#define KTOT (D * (NT + 1))   // 512
#define TM 32                 // nodes per fused block
#define TCAP 12               // per-(node,type) csr capacity
#define NCAP (3 * TCAP)       // 36 slots per node

typedef __attribute__((ext_vector_type(8))) __bf16 bf16x8;
typedef __attribute__((ext_vector_type(4))) float f32x4;

__device__ inline unsigned short f2bf(float f) {
    unsigned int u = __float_as_uint(f);
    unsigned int r = (u + 0x7FFFu + ((u >> 16) & 1u)) >> 16;
    return (unsigned short)r;
}
__device__ inline float bf2f(unsigned int low16) {
    return __uint_as_float(low16 << 16);
}

// ---------------- zero helper (fallback path) ----------------
__global__ void zero_kernel(float* __restrict__ p, long long n4) {
    long long i = (long long)blockIdx.x * blockDim.x + threadIdx.x;
    long long stride = (long long)gridDim.x * blockDim.x;
    float4 z = make_float4(0.f, 0.f, 0.f, 0.f);
    for (; i < n4; i += stride) ((float4*)p)[i] = z;
}

// ---------------- prep: softmax(attention) -> wcat, biasb, bfrag; zero deg/ovfc ----------------
__global__ void prep_kernel(const float* __restrict__ W_edge, const float* __restrict__ b_edge,
                            const float* __restrict__ W_self, const float* __restrict__ b_self,
                            const float* __restrict__ attention,
                            float* __restrict__ wcat, float* __restrict__ biasb,
                            unsigned short* __restrict__ bfrag,
                            int* __restrict__ zeroMe, int zeroN) {
    float a0 = attention[0], a1 = attention[1], a2 = attention[2], a3 = attention[3];
    float m = fmaxf(fmaxf(a0, a1), fmaxf(a2, a3));
    float e0 = expf(a0 - m), e1 = expf(a1 - m), e2 = expf(a2 - m), e3 = expf(a3 - m);
    float inv = 1.f / (e0 + e1 + e2 + e3);
    float at[4] = {e0 * inv, e1 * inv, e2 * inv, e3 * inv};

    int idx0 = blockIdx.x * blockDim.x + threadIdx.x;
    int stride = gridDim.x * blockDim.x;
    if (zeroMe) {
        for (int i = idx0; i < zeroN; i += stride) zeroMe[i] = 0;
    }
    for (int i = idx0; i < KTOT * D; i += stride) {
        int k = i >> 7, j = i & (D - 1);
        float v;
        if (k < D) {
            v = at[NT] * W_self[k * D + j];
        } else {
            int t = (k - D) >> 7;
            int kk = (k - D) & (D - 1);
            v = at[t] * W_edge[(t * D + kk) * D + j];
        }
        wcat[i] = v;
    }
    for (int i = idx0; i < KTOT; i += stride) {
        if (i < NT * D) {
            int t = i >> 7, j = i & (D - 1);
            biasb[i] = at[t] * b_edge[t * D + j];
        } else {
            biasb[i] = at[NT] * b_self[i - NT * D];
        }
    }
    if (bfrag) {
        // bfrag: [(step*8+cf)*64+lane]*8 ; B[k][col], col=cf*16+(l&15), k=step*32+(l>>4)*8+j
        for (int i = idx0; i < 16 * 8 * 64; i += stride) {
            int l = i & 63;
            int cf = (i >> 6) & 7;
            int step = i >> 9;
            int col = cf * 16 + (l & 15);
            int kb = step * 32 + ((l >> 4) * 8);
#pragma unroll
            for (int j = 0; j < 8; ++j) {
                int k = kb + j;
                float v;
                if (k < D) {
                    v = at[NT] * W_self[k * D + col];
                } else {
                    int t = (k - D) >> 7;
                    int kk = (k - D) & (D - 1);
                    v = at[t] * W_edge[(t * D + kk) * D + col];
                }
                bfrag[(size_t)i * 8 + j] = f2bf(v);
            }
        }
    }
}

// ---------------- merged per-thread: 1 edge fill (bitfield deg, type-segmented csr) + x->bf16 ----------------
__global__ __launch_bounds__(256) void xcvt_fill_kernel(
    const float* __restrict__ x, unsigned short* __restrict__ xb, int nN,
    const int* __restrict__ ei, const int* __restrict__ et, const float* __restrict__ ew,
    int* __restrict__ deg, int2* __restrict__ csr, int* __restrict__ ovfcnt,
    int* __restrict__ ovflist, int nE) {
    int e = blockIdx.x * blockDim.x + threadIdx.x;

    // issue edge loads early
    int dst = 0, src = 0, t = 0;
    float w = 0.f;
    bool act = (e < nE);
    if (act) {
        dst = ei[nE + e];
        src = ei[e];
        t = et[e];
        w = ew[e];
    }

    // streaming xcvt (hides edge-load latency)
    int total = nN * (D / 4);
    int stride = gridDim.x * blockDim.x;
    for (int i = e; i < total; i += stride) {
        int n = i >> 5;
        int c4 = (i & 31) * 4;
        float4 v = *(const float4*)(x + (size_t)n * D + c4);
        ushort4 o;
        o.x = f2bf(v.x); o.y = f2bf(v.y); o.z = f2bf(v.z); o.w = f2bf(v.w);
        *(ushort4*)(xb + (size_t)n * D + c4) = o;
    }

    // edge bucketing: ONE hot counter word per node, 10-bit field per type
    if (act) {
        int old = atomicAdd(deg + dst, 1 << (10 * t));
        int pos = (old >> (10 * t)) & 1023;
        if (pos < TCAP) {
            csr[(size_t)dst * NCAP + t * TCAP + pos] = make_int2(src, __float_as_int(w));
        } else {
            int o = atomicAdd(ovfcnt, 1);
            ovflist[o] = e;
        }
    }
}

// ---------------- fused gather + MFMA GEMM (type-segmented gather, barrier-free GEMM) ----------------
// Block: 32 nodes, 512 threads (8 waves). LDS: A[32][64 chunks of 16B] (chunk XOR swizzle) @0
// (32KB); s[32][3] f32 @32768. Total 33152 -> 4 blocks/CU (32 waves/CU).
__global__ __launch_bounds__(512, 8) void fused_gemm_kernel(
    const unsigned short* __restrict__ xb, const int2* __restrict__ csr,
    const int* __restrict__ deg, const unsigned short* __restrict__ bfrag,
    const float* __restrict__ biasb,
    const int* __restrict__ ei, const int* __restrict__ et, const float* __restrict__ ew,
    const int* __restrict__ ovfc, const int* __restrict__ ovfl,
    float* __restrict__ out, int nN, int nE) {
    __shared__ unsigned char lds[33152];
    float* sL = (float*)(lds + 32768);
    int t = threadIdx.x;
    int w = t >> 6;
    int lane = t & 63;
    int gl = lane & 15;
    int gbase = lane & 48;
    int row0 = blockIdx.x * TM;

    // ---------- gather phase: wave w owns nodes row0 + w*4 .. +3 (16 lanes/node) ----------
    int lrow = w * 4 + (lane >> 4);
    int node = row0 + lrow;
    int nclamp = (node < nN) ? node : (nN - 1);
    int swz = lrow & 15;
    int dgw = (node < nN) ? deg[nclamp] : 0;
    int cnt0 = dgw & 1023;          cnt0 = cnt0 > TCAP ? TCAP : cnt0;
    int cnt1 = (dgw >> 10) & 1023;  cnt1 = cnt1 > TCAP ? TCAP : cnt1;
    int cnt2 = (dgw >> 20) & 1023;  cnt2 = cnt2 > TCAP ? TCAP : cnt2;

    const int2* c = csr + (size_t)nclamp * NCAP;
    int gli = (gl < TCAP) ? gl : (TCAP - 1);
    int2 m0 = c[gli];
    int2 m1 = c[TCAP + gli];
    int2 m2 = c[2 * TCAP + gli];

    // own x row -> LDS (chunk-XOR swizzled, both sides — rule #21)
    {
        uint4 xo = *(const uint4*)(xb + (size_t)nclamp * D + gl * 8);
        *(uint4*)(lds + lrow * 1024 + ((gl ^ swz) << 4)) = xo;
    }

    float sw0 = 0.f, sw1 = 0.f, sw2 = 0.f;

#define ACCP(uA, uB, jj0, jj1)                                                      \
    aacc[jj0] = fmaf(wA, __uint_as_float((uA) << 16), aacc[jj0]);                   \
    aacc[jj1] = fmaf(wA, __uint_as_float((uA) & 0xFFFF0000u), aacc[jj1]);           \
    aacc[jj0] = fmaf(wB, __uint_as_float((uB) << 16), aacc[jj0]);                   \
    aacc[jj1] = fmaf(wB, __uint_as_float((uB) & 0xFFFF0000u), aacc[jj1]);

#define TYPELOOP(mt, cntt, swt, tt) do {                                            \
    float aacc[8];                                                                  \
    _Pragma("unroll") for (int j = 0; j < 8; ++j) aacc[j] = 0.f;                    \
    for (int i = 0; i < cntt; i += 2) {                                             \
        int exA = __shfl(mt.x, gbase + i);                                          \
        int ewA = __shfl(mt.y, gbase + i);                                          \
        int exB = __shfl(mt.x, gbase + i + 1);                                      \
        int ewB = __shfl(mt.y, gbase + i + 1);                                      \
        bool actB = (i + 1 < cntt);                                                 \
        int srcA = exA; if ((unsigned)srcA >= (unsigned)nN) srcA = 0;               \
        int srcB = actB ? exB : 0; if ((unsigned)srcB >= (unsigned)nN) srcB = 0;    \
        float wA = __int_as_float(ewA);                                             \
        float wB = actB ? __int_as_float(ewB) : 0.f;                                \
        uint4 xa = *(const uint4*)(xb + (size_t)srcA * D + gl * 8);                 \
        uint4 xv = *(const uint4*)(xb + (size_t)srcB * D + gl * 8);                 \
        swt += wA + wB;                                                             \
        ACCP(xa.x, xv.x, 0, 1) ACCP(xa.y, xv.y, 2, 3)                               \
        ACCP(xa.z, xv.z, 4, 5) ACCP(xa.w, xv.w, 6, 7)                               \
    }                                                                               \
    uint4 o;                                                                        \
    o.x = (unsigned)f2bf(aacc[0]) | ((unsigned)f2bf(aacc[1]) << 16);                \
    o.y = (unsigned)f2bf(aacc[2]) | ((unsigned)f2bf(aacc[3]) << 16);                \
    o.z = (unsigned)f2bf(aacc[4]) | ((unsigned)f2bf(aacc[5]) << 16);                \
    o.w = (unsigned)f2bf(aacc[6]) | ((unsigned)f2bf(aacc[7]) << 16);                \
    *(uint4*)(lds + lrow * 1024 + 256 + (tt) * 256 + ((gl ^ swz) << 4)) = o;        \
} while (0)

    TYPELOOP(m0, cnt0, sw0, 0);
    TYPELOOP(m1, cnt1, sw1, 1);
    TYPELOOP(m2, cnt2, sw2, 2);
#undef TYPELOOP
#undef ACCP

    if (gl < 3) {
        float sv = (gl == 0) ? sw0 : ((gl == 1) ? sw1 : sw2);
        sL[lrow * NT + gl] = sv;
    }
    __syncthreads();

    // ---------- overflow patch (cnt == 0 in practice; correct for any data) ----------
    int cnt = *ovfc;
    if (cnt > 0) {
        if (w == 0 && lane < 16) {
            for (int i = 0; i < cnt; ++i) {
                int e = ovfl[i];
                int dst = ei[nE + e];
                if (dst >= row0 && dst < row0 + TM && dst < nN) {
                    int tt = et[e];
                    float wt = ew[e];
                    int src = ei[e];
                    int lr = dst - row0;
                    uint4* p = (uint4*)(lds + lr * 1024 + 256 + tt * 256 + ((lane ^ (lr & 15)) << 4));
                    uint4 cu = *p;
                    uint4 xr = *(const uint4*)(xb + (size_t)src * D + lane * 8);
                    float f0 = bf2f(cu.x & 0xFFFF) + wt * bf2f(xr.x & 0xFFFF);
                    float f1 = bf2f(cu.x >> 16)    + wt * bf2f(xr.x >> 16);
                    float f2 = bf2f(cu.y & 0xFFFF) + wt * bf2f(xr.y & 0xFFFF);
                    float f3 = bf2f(cu.y >> 16)    + wt * bf2f(xr.y >> 16);
                    float f4 = bf2f(cu.z & 0xFFFF) + wt * bf2f(xr.z & 0xFFFF);
                    float f5 = bf2f(cu.z >> 16)    + wt * bf2f(xr.z >> 16);
                    float f6 = bf2f(cu.w & 0xFFFF) + wt * bf2f(xr.w & 0xFFFF);
                    float f7 = bf2f(cu.w >> 16)    + wt * bf2f(xr.w >> 16);
                    cu.x = (unsigned int)f2bf(f0) | ((unsigned int)f2bf(f1) << 16);
                    cu.y = (unsigned int)f2bf(f2) | ((unsigned int)f2bf(f3) << 16);
                    cu.z = (unsigned int)f2bf(f4) | ((unsigned int)f2bf(f5) << 16);
                    cu.w = (unsigned int)f2bf(f6) | ((unsigned int)f2bf(f7) << 16);
                    *p = cu;
                    if (lane == 0) sL[lr * NT + tt] += wt;
                }
            }
        }
        __syncthreads();
    }

    // ---------- GEMM phase: 16 K-steps, wave w -> cols w*16..+15, NO barriers ----------
    int ll = lane & 15;
    int ck = lane >> 4;
    f32x4 acc0 = (f32x4){0.f, 0.f, 0.f, 0.f};
    f32x4 acc1 = (f32x4){0.f, 0.f, 0.f, 0.f};
#pragma unroll 4
    for (int st = 0; st < 16; ++st) {
        bf16x8 b = *(const bf16x8*)(bfrag + (size_t)st * 4096 + w * 512 + lane * 8);
        int cc = st * 4 + ck;
        int phys = (cc & 48) | ((cc & 15) ^ ll);
        bf16x8 a0 = *(const bf16x8*)(lds + ll * 1024 + (phys << 4));
        bf16x8 a1 = *(const bf16x8*)(lds + (16 + ll) * 1024 + (phys << 4));
        acc0 = __builtin_amdgcn_mfma_f32_16x16x32_bf16(a0, b, acc0, 0, 0, 0);
        acc1 = __builtin_amdgcn_mfma_f32_16x16x32_bf16(a1, b, acc1, 0, 0, 0);
    }

    // ---------- epilogue ----------
    int colb = w * 16 + ll;
    float bb0 = biasb[colb], bb1 = biasb[D + colb], bb2 = biasb[2 * D + colb], bs4 = biasb[3 * D + colb];
    const float kInvSqrt2 = 0.70710678118654752440f;
#pragma unroll
    for (int fr = 0; fr < 2; ++fr) {
        f32x4 A = fr ? acc1 : acc0;
#pragma unroll
        for (int reg = 0; reg < 4; ++reg) {
            int lr = fr * 16 + ck * 4 + reg;
            long row = (long)row0 + lr;
            if (row >= nN) continue;
            float s0 = sL[lr * NT + 0];
            float s1 = sL[lr * NT + 1];
            float s2 = sL[lr * NT + 2];
            float v = A[reg] + bs4 + s0 * bb0 + s1 * bb1 + s2 * bb2;
            v = 0.5f * v * (1.f + erff(v * kInvSqrt2));
            out[row * D + colb] = v;
        }
    }
}

// ================= FALLBACK PATH (small ws): f32 atomic scatter + f32 GEMM =================
__global__ __launch_bounds__(256) void scatterA_kernel(
    const float* __restrict__ x, const int* __restrict__ ei,
    const int* __restrict__ et, const float* __restrict__ ew,
    float* __restrict__ agg, float* __restrict__ s, int nE) {
    int gtid = blockIdx.x * blockDim.x + threadIdx.x;
    int wave = gtid >> 6;
    int lane = threadIdx.x & 63;
    int nw = (gridDim.x * blockDim.x) >> 6;
    for (int e = wave; e < nE; e += nw) {
        int src = ei[e];
        int dst = ei[nE + e];
        int t = et[e];
        float w = ew[e];
        float2 xv = *(const float2*)(x + (size_t)src * D + lane * 2);
        float* p = agg + (size_t)dst * (NT * D) + t * D + lane * 2;
        unsafeAtomicAdd(p, w * xv.x);
        unsafeAtomicAdd(p + 1, w * xv.y);
        if (lane == 0) unsafeAtomicAdd(s + (size_t)dst * NT + t, w);
    }
}

#define BM 64
#define BK 32
__global__ __launch_bounds__(256) void gemm_gelu_kernel(
    const float* __restrict__ x, const float* __restrict__ agg,
    const float* __restrict__ s, const float* __restrict__ wcat,
    const float* __restrict__ biasb, float* __restrict__ out, int nNodes) {
    __shared__ float As[BK][BM + 1];
    __shared__ float Bs[BK][D];

    int tx = threadIdx.x;
    int row0 = blockIdx.x * BM;
    int cg = tx & 31;
    int rg = tx >> 5;
    int lr = tx >> 3;
    int lc = (tx & 7) * 4;

    float acc[8][4];
#pragma unroll
    for (int i = 0; i < 8; ++i)
#pragma unroll
        for (int j = 0; j < 4; ++j) acc[i][j] = 0.f;

    for (int k0 = 0; k0 < KTOT; k0 += BK) {
        const float* srcBase;
        int strideA, koff;
        if (k0 < D) { srcBase = x; strideA = D; koff = k0; }
        else        { srcBase = agg; strideA = NT * D; koff = k0 - D; }
#pragma unroll
        for (int h = 0; h < 2; ++h) {
            int r = lr + h * 32;
            int node = row0 + r;
            if (node >= nNodes) node = nNodes - 1;
            float4 v = *(const float4*)(srcBase + (size_t)node * strideA + koff + lc);
            As[lc + 0][r] = v.x; As[lc + 1][r] = v.y;
            As[lc + 2][r] = v.z; As[lc + 3][r] = v.w;
        }
        {
            int br = tx >> 5;
            int bc = (tx & 31) * 4;
#pragma unroll
            for (int h = 0; h < 4; ++h) {
                int r = br + h * 8;
                *(float4*)(&Bs[r][bc]) = *(const float4*)(wcat + (size_t)(k0 + r) * D + bc);
            }
        }
        __syncthreads();
#pragma unroll
        for (int kk = 0; kk < BK; ++kk) {
            float4 b = *(const float4*)(&Bs[kk][cg * 4]);
            float a[8];
            *(float4*)(a)     = *(const float4*)(&As[kk][rg * 8]);
            *(float4*)(a + 4) = *(const float4*)(&As[kk][rg * 8 + 4]);
#pragma unroll
            for (int i = 0; i < 8; ++i) {
                acc[i][0] = fmaf(a[i], b.x, acc[i][0]);
                acc[i][1] = fmaf(a[i], b.y, acc[i][1]);
                acc[i][2] = fmaf(a[i], b.z, acc[i][2]);
                acc[i][3] = fmaf(a[i], b.w, acc[i][3]);
            }
        }
        __syncthreads();
    }

    int jc = cg * 4;
    float4 bb0 = *(const float4*)(biasb + 0 * D + jc);
    float4 bb1 = *(const float4*)(biasb + 1 * D + jc);
    float4 bb2 = *(const float4*)(biasb + 2 * D + jc);
    float4 bsv = *(const float4*)(biasb + NT * D + jc);
#pragma unroll
    for (int i = 0; i < 8; ++i) {
        int node = row0 + rg * 8 + i;
        if (node >= nNodes) break;
        float s0 = s[(size_t)node * NT + 0];
        float s1 = s[(size_t)node * NT + 1];
        float s2 = s[(size_t)node * NT + 2];
        float4 r;
        r.x = acc[i][0] + bsv.x + s0 * bb0.x + s1 * bb1.x + s2 * bb2.x;
        r.y = acc[i][1] + bsv.y + s0 * bb0.y + s1 * bb1.y + s2 * bb2.y;
        r.z = acc[i][2] + bsv.z + s0 * bb0.z + s1 * bb1.z + s2 * bb2.z;
        r.w = acc[i][3] + bsv.w + s0 * bb0.w + s1 * bb1.w + s2 * bb2.w;
        const float kInvSqrt2 = 0.70710678118654752440f;
        r.x = 0.5f * r.x * (1.f + erff(r.x * kInvSqrt2));
        r.y = 0.5f * r.y * (1.f + erff(r.y * kInvSqrt2));
        r.z = 0.5f * r.z * (1.f + erff(r.z * kInvSqrt2));
        r.w = 0.5f * r.w * (1.f + erff(r.w * kInvSqrt2));
        *(float4*)(out + (size_t)node * D + jc) = r;
    }
}

// ================= PATH C: zero-workspace fallback =================
__global__ __launch_bounds__(256) void selfmv_kernel(
    const float* __restrict__ x, const float* __restrict__ Ws,
    const float* __restrict__ bs, const float* __restrict__ attn,
    float* __restrict__ out, int nN) {
    float a0 = attn[0], a1 = attn[1], a2 = attn[2], a3 = attn[3];
    float m = fmaxf(fmaxf(a0, a1), fmaxf(a2, a3));
    float e3 = expf(a3 - m);
    float inv = 1.f / (expf(a0 - m) + expf(a1 - m) + expf(a2 - m) + e3);
    float at3 = e3 * inv;
    int wave = (blockIdx.x * blockDim.x + threadIdx.x) >> 6;
    int lane = threadIdx.x & 63;
    int nw = (gridDim.x * blockDim.x) >> 6;
    for (int n = wave; n < nN; n += nw) {
        float2 xr = *(const float2*)(x + (size_t)n * D + lane * 2);
        float acc0 = 0.f, acc1 = 0.f;
#pragma unroll
        for (int k = 0; k < D; ++k) {
            float xv = __shfl((k & 1) ? xr.y : xr.x, k >> 1);
            float2 wv = *(const float2*)(Ws + (size_t)k * D + lane * 2);
            acc0 = fmaf(xv, wv.x, acc0);
            acc1 = fmaf(xv, wv.y, acc1);
        }
        float2 r;
        r.x = at3 * (acc0 + bs[lane * 2]);
        r.y = at3 * (acc1 + bs[lane * 2 + 1]);
        *(float2*)(out + (size_t)n * D + lane * 2) = r;
    }
}

__global__ __launch_bounds__(256) void edgemv_kernel(
    const float* __restrict__ x, const int* __restrict__ ei,
    const int* __restrict__ et, const float* __restrict__ ew,
    const float* __restrict__ We, const float* __restrict__ be,
    const float* __restrict__ attn, float* __restrict__ out, int nE) {
    float a0 = attn[0], a1 = attn[1], a2 = attn[2], a3 = attn[3];
    float m = fmaxf(fmaxf(a0, a1), fmaxf(a2, a3));
    float e0 = expf(a0 - m), e1 = expf(a1 - m), e2 = expf(a2 - m), e3 = expf(a3 - m);
    float inv = 1.f / (e0 + e1 + e2 + e3);
    float at[NT] = {e0 * inv, e1 * inv, e2 * inv};
    int wave = (blockIdx.x * blockDim.x + threadIdx.x) >> 6;
    int lane = threadIdx.x & 63;
    int nw = (gridDim.x * blockDim.x) >> 6;
    for (int e = wave; e < nE; e += nw) {
        int src = ei[e];
        int dst = ei[nE + e];
        int t = et[e];
        float sc = ew[e] * at[t];
        const float* W = We + (size_t)t * D * D;
        float2 xr = *(const float2*)(x + (size_t)src * D + lane * 2);
        float acc0 = 0.f, acc1 = 0.f;
#pragma unroll
        for (int k = 0; k < D; ++k) {
            float xv = __shfl((k & 1) ? xr.y : xr.x, k >> 1);
            float2 wv = *(const float2*)(W + (size_t)k * D + lane * 2);
            acc0 = fmaf(xv, wv.x, acc0);
            acc1 = fmaf(xv, wv.y, acc1);
        }
        float* p = out + (size_t)dst * D + lane * 2;
        unsafeAtomicAdd(p,     sc * (acc0 + be[(size_t)t * D + lane * 2]));
        unsafeAtomicAdd(p + 1, sc * (acc1 + be[(size_t)t * D + lane * 2 + 1]));
    }
}

__global__ void gelu_kernel(float* __restrict__ p, long long n4) {
    long long i = (long long)blockIdx.x * blockDim.x + threadIdx.x;
    long long stride = (long long)gridDim.x * blockDim.x;
    const float kInvSqrt2 = 0.70710678118654752440f;
    for (; i < n4; i += stride) {
        float4 r = ((float4*)p)[i];
        r.x = 0.5f * r.x * (1.f + erff(r.x * kInvSqrt2));
        r.y = 0.5f * r.y * (1.f + erff(r.y * kInvSqrt2));
        r.z = 0.5f * r.z * (1.f + erff(r.z * kInvSqrt2));
        r.w = 0.5f * r.w * (1.f + erff(r.w * kInvSqrt2));
        ((float4*)p)[i] = r;
    }
}

extern "C" void kernel_launch(void* const* d_in, const int* in_sizes, int n_in,
                              void* d_out, int out_size, void* d_ws, size_t ws_size,
                              hipStream_t stream) {
    const float* x = (const float*)d_in[0];
    const int* ei = (const int*)d_in[1];      // int64 in reference -> int32 here
    const int* et = (const int*)d_in[2];
    const float* ew = (const float*)d_in[3];
    const float* W_edge = (const float*)d_in[4];
    const float* b_edge = (const float*)d_in[5];
    const float* W_self = (const float*)d_in[6];
    const float* b_self = (const float*)d_in[7];
    const float* attention = (const float*)d_in[8];
    float* out = (float*)d_out;

    const int nN = in_sizes[0] / D;   // 100000
    const int nE = in_sizes[2];       // 600000

    // ---- fused path workspace (16B-aligned sections) ----
    size_t off = 0;
    auto take = [&](size_t bytes) { size_t o = (off + 15) & ~(size_t)15; off = o + bytes; return o; };
    size_t o_wcat  = take((size_t)KTOT * D * 4);
    size_t o_biasb = take((size_t)KTOT * 4);
    size_t o_bfrag = take(131072);
    size_t o_deg   = take(((size_t)nN + 2) * 4);          // deg[nN] (3x10-bit fields) + ovfc
    size_t o_ovfl  = take((size_t)nE * 4);
    size_t o_csr   = take((size_t)nN * NCAP * 8);
    size_t o_xb    = take((size_t)nN * D * 2);
    size_t needFused = off;

    if (ws_size >= needFused && nN < (1 << 20)) {
        char* ws = (char*)d_ws;
        float* wcat = (float*)(ws + o_wcat);
        float* biasb = (float*)(ws + o_biasb);
        unsigned short* bfrag = (unsigned short*)(ws + o_bfrag);
        int* deg = (int*)(ws + o_deg);
        int* ovfc = deg + nN;
        int* ovfl = (int*)(ws + o_ovfl);
        int2* csr = (int2*)(ws + o_csr);
        unsigned short* xb = (unsigned short*)(ws + o_xb);

        hipLaunchKernelGGL(prep_kernel, dim3(64), dim3(256), 0, stream,
                           W_edge, b_edge, W_self, b_self, attention, wcat, biasb, bfrag,
                           deg, nN + 2);
        hipLaunchKernelGGL(xcvt_fill_kernel, dim3((nE + 255) / 256), dim3(256), 0, stream,
                           x, xb, nN, ei, et, ew, deg, csr, ovfc, ovfl, nE);
        hipLaunchKernelGGL(fused_gemm_kernel, dim3((nN + TM - 1) / TM), dim3(512), 0, stream,
                           xb, csr, deg, bfrag, biasb, ei, et, ew, ovfc, ovfl, out, nN, nE);
        return;
    }

    const size_t baseFloats = (size_t)nN * NT * D + (size_t)nN * NT + (size_t)KTOT * D + KTOT;
    if (ws_size >= baseFloats * 4) {
        float* agg = (float*)d_ws;
        float* sW = agg + (size_t)nN * NT * D;
        float* wcat = sW + (size_t)nN * NT;
        float* biasb = wcat + (size_t)KTOT * D;
        long long zeroFloats = (long long)nN * (NT * D + NT);
        hipLaunchKernelGGL(zero_kernel, dim3(2048), dim3(256), 0, stream, agg, (zeroFloats + 3) / 4);
        hipLaunchKernelGGL(prep_kernel, dim3(64), dim3(256), 0, stream,
                           W_edge, b_edge, W_self, b_self, attention, wcat, biasb,
                           (unsigned short*)nullptr, (int*)nullptr, 0);
        hipLaunchKernelGGL(scatterA_kernel, dim3(2048), dim3(256), 0, stream,
                           x, ei, et, ew, agg, sW, nE);
        hipLaunchKernelGGL(gemm_gelu_kernel, dim3((nN + BM - 1) / BM), dim3(256), 0, stream,
                           x, agg, sW, wcat, biasb, out, nN);
    } else {
        hipLaunchKernelGGL(selfmv_kernel, dim3(2048), dim3(256), 0, stream,
                           x, W_self, b_self, attention, out, nN);
        hipLaunchKernelGGL(edgemv_kernel, dim3(2048), dim3(256), 0, stream,
                           x, ei, et, ew, W_edge, b_edge, attention, out, nE);
        hipLaunchKernelGGL(gelu_kernel, dim3(2048), dim3(256), 0, stream,
                           out, (long long)nN * D / 4);
    }
}

// Round 14
// 110.069 us; speedup vs baseline: 1.1203x; 1.0925x over previous
//
#include <hip/hip_runtime.h>
#include <hip/hip_bf16.h>
#include <math.h>

#define D 128
#define NT 3
#define KTOT (D * (NT + 1))   // 512
#define TM 32                 // nodes per fused block
#define TCAP 12               // per-(node,type) csr capacity
#define NCAP (3 * TCAP)       // 36 slots per node

typedef __attribute__((ext_vector_type(8))) __bf16 bf16x8;
typedef __attribute__((ext_vector_type(4))) float f32x4;

__device__ inline unsigned short f2bf(float f) {
    unsigned int u = __float_as_uint(f);
    unsigned int r = (u + 0x7FFFu + ((u >> 16) & 1u)) >> 16;
    return (unsigned short)r;
}
__device__ inline float bf2f(unsigned int low16) {
    return __uint_as_float(low16 << 16);
}
// packed RNE f32x2 -> bf16x2 (v_cvt_pk_bf16_f32)
__device__ inline unsigned int pk2(float a, float b) {
    __hip_bfloat162 h = __float22bfloat162_rn(make_float2(a, b));
    return *(unsigned int*)&h;
}

// ---------------- zero helper (fallback path) ----------------
__global__ void zero_kernel(float* __restrict__ p, long long n4) {
    long long i = (long long)blockIdx.x * blockDim.x + threadIdx.x;
    long long stride = (long long)gridDim.x * blockDim.x;
    float4 z = make_float4(0.f, 0.f, 0.f, 0.f);
    for (; i < n4; i += stride) ((float4*)p)[i] = z;
}

// ---------------- prep: softmax(attention) -> wcat, biasb, bfrag; zero deg/ovfc ----------------
__global__ void prep_kernel(const float* __restrict__ W_edge, const float* __restrict__ b_edge,
                            const float* __restrict__ W_self, const float* __restrict__ b_self,
                            const float* __restrict__ attention,
                            float* __restrict__ wcat, float* __restrict__ biasb,
                            unsigned short* __restrict__ bfrag,
                            int* __restrict__ zeroMe, int zeroN) {
    float a0 = attention[0], a1 = attention[1], a2 = attention[2], a3 = attention[3];
    float m = fmaxf(fmaxf(a0, a1), fmaxf(a2, a3));
    float e0 = expf(a0 - m), e1 = expf(a1 - m), e2 = expf(a2 - m), e3 = expf(a3 - m);
    float inv = 1.f / (e0 + e1 + e2 + e3);
    float at[4] = {e0 * inv, e1 * inv, e2 * inv, e3 * inv};

    int idx0 = blockIdx.x * blockDim.x + threadIdx.x;
    int stride = gridDim.x * blockDim.x;
    if (zeroMe) {
        for (int i = idx0; i < zeroN; i += stride) zeroMe[i] = 0;
    }
    for (int i = idx0; i < KTOT * D; i += stride) {
        int k = i >> 7, j = i & (D - 1);
        float v;
        if (k < D) {
            v = at[NT] * W_self[k * D + j];
        } else {
            int t = (k - D) >> 7;
            int kk = (k - D) & (D - 1);
            v = at[t] * W_edge[(t * D + kk) * D + j];
        }
        wcat[i] = v;
    }
    for (int i = idx0; i < KTOT; i += stride) {
        if (i < NT * D) {
            int t = i >> 7, j = i & (D - 1);
            biasb[i] = at[t] * b_edge[t * D + j];
        } else {
            biasb[i] = at[NT] * b_self[i - NT * D];
        }
    }
    if (bfrag) {
        // bfrag: [(step*8+cf)*64+lane]*8 ; B[k][col], col=cf*16+(l&15), k=step*32+(l>>4)*8+j
        for (int i = idx0; i < 16 * 8 * 64; i += stride) {
            int l = i & 63;
            int cf = (i >> 6) & 7;
            int step = i >> 9;
            int col = cf * 16 + (l & 15);
            int kb = step * 32 + ((l >> 4) * 8);
#pragma unroll
            for (int j = 0; j < 8; ++j) {
                int k = kb + j;
                float v;
                if (k < D) {
                    v = at[NT] * W_self[k * D + col];
                } else {
                    int t = (k - D) >> 7;
                    int kk = (k - D) & (D - 1);
                    v = at[t] * W_edge[(t * D + kk) * D + col];
                }
                bfrag[(size_t)i * 8 + j] = f2bf(v);
            }
        }
    }
}

// ---------------- merged per-thread: edge fill (atomic hidden under xcvt) + x->bf16 ----------------
__global__ __launch_bounds__(256) void xcvt_fill_kernel(
    const float* __restrict__ x, unsigned short* __restrict__ xb, int nN,
    const int* __restrict__ ei, const int* __restrict__ et, const float* __restrict__ ew,
    int* __restrict__ deg, int2* __restrict__ csr, int* __restrict__ ovfcnt,
    int* __restrict__ ovflist, int nE) {
    int e = blockIdx.x * blockDim.x + threadIdx.x;

    // issue edge loads early
    int dst = 0, src = 0, t = 0;
    float w = 0.f;
    bool act = (e < nE);
    if (act) {
        dst = ei[nE + e];
        src = ei[e];
        t = et[e];
        w = ew[e];
    }

    // issue the counter atomic NOW — its ~600cy latency hides under the xcvt stream
    int pos = 0;
    if (act) {
        int old = atomicAdd(deg + dst, 1 << (10 * t));
        pos = (old >> (10 * t)) & 1023;
    }

    // streaming xcvt (covers edge-load + atomic latency)
    int total = nN * (D / 4);
    int stride = gridDim.x * blockDim.x;
    for (int i = e; i < total; i += stride) {
        int n = i >> 5;
        int c4 = (i & 31) * 4;
        float4 v = *(const float4*)(x + (size_t)n * D + c4);
        uint2 o;
        o.x = pk2(v.x, v.y);
        o.y = pk2(v.z, v.w);
        *(uint2*)(xb + (size_t)n * D + c4) = o;
    }

    // csr write (atomic result long since returned)
    if (act) {
        if (pos < TCAP) {
            csr[(size_t)dst * NCAP + t * TCAP + pos] = make_int2(src, __float_as_int(w));
        } else {
            int o = atomicAdd(ovfcnt, 1);
            ovflist[o] = e;
        }
    }
}

// ---------------- fused gather + MFMA GEMM (type-segmented gather, barrier-free GEMM) ----------------
// Block: 32 nodes, 512 threads (8 waves). LDS: A[32][64 chunks of 16B] (chunk XOR swizzle) @0
// (32KB); s[32][3] f32 @32768. Total 33152 -> 4 blocks/CU (32 waves/CU).
__global__ __launch_bounds__(512, 8) void fused_gemm_kernel(
    const unsigned short* __restrict__ xb, const int2* __restrict__ csr,
    const int* __restrict__ deg, const unsigned short* __restrict__ bfrag,
    const float* __restrict__ biasb,
    const int* __restrict__ ei, const int* __restrict__ et, const float* __restrict__ ew,
    const int* __restrict__ ovfc, const int* __restrict__ ovfl,
    float* __restrict__ out, int nN, int nE) {
    __shared__ unsigned char lds[33152];
    float* sL = (float*)(lds + 32768);
    int t = threadIdx.x;
    int w = t >> 6;
    int lane = t & 63;
    int gl = lane & 15;
    int gbase = lane & 48;
    int row0 = blockIdx.x * TM;

    // ---------- gather phase: wave w owns nodes row0 + w*4 .. +3 (16 lanes/node) ----------
    int lrow = w * 4 + (lane >> 4);
    int node = row0 + lrow;
    int nclamp = (node < nN) ? node : (nN - 1);
    int swz = lrow & 15;
    int dgw = (node < nN) ? deg[nclamp] : 0;
    int cnt0 = dgw & 1023;          cnt0 = cnt0 > TCAP ? TCAP : cnt0;
    int cnt1 = (dgw >> 10) & 1023;  cnt1 = cnt1 > TCAP ? TCAP : cnt1;
    int cnt2 = (dgw >> 20) & 1023;  cnt2 = cnt2 > TCAP ? TCAP : cnt2;

    const int2* c = csr + (size_t)nclamp * NCAP;
    int gli = (gl < TCAP) ? gl : (TCAP - 1);
    int2 m0 = c[gli];
    int2 m1 = c[TCAP + gli];
    int2 m2 = c[2 * TCAP + gli];

    // own x row -> LDS (chunk-XOR swizzled, both sides — rule #21)
    {
        uint4 xo = *(const uint4*)(xb + (size_t)nclamp * D + gl * 8);
        *(uint4*)(lds + lrow * 1024 + ((gl ^ swz) << 4)) = xo;
    }

    float sw0 = 0.f, sw1 = 0.f, sw2 = 0.f;

#define ACCP(uA, uB, jj0, jj1)                                                      \
    aacc[jj0] = fmaf(wA, __uint_as_float((uA) << 16), aacc[jj0]);                   \
    aacc[jj1] = fmaf(wA, __uint_as_float((uA) & 0xFFFF0000u), aacc[jj1]);           \
    aacc[jj0] = fmaf(wB, __uint_as_float((uB) << 16), aacc[jj0]);                   \
    aacc[jj1] = fmaf(wB, __uint_as_float((uB) & 0xFFFF0000u), aacc[jj1]);

#define TYPELOOP(mt, cntt, swt, tt) do {                                            \
    float aacc[8];                                                                  \
    _Pragma("unroll") for (int j = 0; j < 8; ++j) aacc[j] = 0.f;                    \
    for (int i = 0; i < cntt; i += 2) {                                             \
        int exA = __shfl(mt.x, gbase + i);                                          \
        int ewA = __shfl(mt.y, gbase + i);                                          \
        int exB = __shfl(mt.x, gbase + i + 1);                                      \
        int ewB = __shfl(mt.y, gbase + i + 1);                                      \
        bool actB = (i + 1 < cntt);                                                 \
        int srcA = exA; if ((unsigned)srcA >= (unsigned)nN) srcA = 0;               \
        int srcB = actB ? exB : 0; if ((unsigned)srcB >= (unsigned)nN) srcB = 0;    \
        float wA = __int_as_float(ewA);                                             \
        float wB = actB ? __int_as_float(ewB) : 0.f;                                \
        uint4 xa = *(const uint4*)(xb + (size_t)srcA * D + gl * 8);                 \
        uint4 xv = *(const uint4*)(xb + (size_t)srcB * D + gl * 8);                 \
        swt += wA + wB;                                                             \
        ACCP(xa.x, xv.x, 0, 1) ACCP(xa.y, xv.y, 2, 3)                               \
        ACCP(xa.z, xv.z, 4, 5) ACCP(xa.w, xv.w, 6, 7)                               \
    }                                                                               \
    uint4 o;                                                                        \
    o.x = pk2(aacc[0], aacc[1]);                                                    \
    o.y = pk2(aacc[2], aacc[3]);                                                    \
    o.z = pk2(aacc[4], aacc[5]);                                                    \
    o.w = pk2(aacc[6], aacc[7]);                                                    \
    *(uint4*)(lds + lrow * 1024 + 256 + (tt) * 256 + ((gl ^ swz) << 4)) = o;        \
} while (0)

    TYPELOOP(m0, cnt0, sw0, 0);
    TYPELOOP(m1, cnt1, sw1, 1);
    TYPELOOP(m2, cnt2, sw2, 2);
#undef TYPELOOP
#undef ACCP

    if (gl < 3) {
        float sv = (gl == 0) ? sw0 : ((gl == 1) ? sw1 : sw2);
        sL[lrow * NT + gl] = sv;
    }
    __syncthreads();

    // ---------- overflow patch (cnt == 0 in practice; correct for any data) ----------
    int cnt = *ovfc;
    if (cnt > 0) {
        if (w == 0 && lane < 16) {
            for (int i = 0; i < cnt; ++i) {
                int e = ovfl[i];
                int dst = ei[nE + e];
                if (dst >= row0 && dst < row0 + TM && dst < nN) {
                    int tt = et[e];
                    float wt = ew[e];
                    int src = ei[e];
                    int lr = dst - row0;
                    uint4* p = (uint4*)(lds + lr * 1024 + 256 + tt * 256 + ((lane ^ (lr & 15)) << 4));
                    uint4 cu = *p;
                    uint4 xr = *(const uint4*)(xb + (size_t)src * D + lane * 8);
                    float f0 = bf2f(cu.x & 0xFFFF) + wt * bf2f(xr.x & 0xFFFF);
                    float f1 = bf2f(cu.x >> 16)    + wt * bf2f(xr.x >> 16);
                    float f2 = bf2f(cu.y & 0xFFFF) + wt * bf2f(xr.y & 0xFFFF);
                    float f3 = bf2f(cu.y >> 16)    + wt * bf2f(xr.y >> 16);
                    float f4 = bf2f(cu.z & 0xFFFF) + wt * bf2f(xr.z & 0xFFFF);
                    float f5 = bf2f(cu.z >> 16)    + wt * bf2f(xr.z >> 16);
                    float f6 = bf2f(cu.w & 0xFFFF) + wt * bf2f(xr.w & 0xFFFF);
                    float f7 = bf2f(cu.w >> 16)    + wt * bf2f(xr.w >> 16);
                    cu.x = (unsigned int)f2bf(f0) | ((unsigned int)f2bf(f1) << 16);
                    cu.y = (unsigned int)f2bf(f2) | ((unsigned int)f2bf(f3) << 16);
                    cu.z = (unsigned int)f2bf(f4) | ((unsigned int)f2bf(f5) << 16);
                    cu.w = (unsigned int)f2bf(f6) | ((unsigned int)f2bf(f7) << 16);
                    *p = cu;
                    if (lane == 0) sL[lr * NT + tt] += wt;
                }
            }
        }
        __syncthreads();
    }

    // ---------- GEMM phase: 16 K-steps, wave w -> cols w*16..+15, NO barriers ----------
    int ll = lane & 15;
    int ck = lane >> 4;
    f32x4 acc0 = (f32x4){0.f, 0.f, 0.f, 0.f};
    f32x4 acc1 = (f32x4){0.f, 0.f, 0.f, 0.f};
#pragma unroll 4
    for (int st = 0; st < 16; ++st) {
        bf16x8 b = *(const bf16x8*)(bfrag + (size_t)st * 4096 + w * 512 + lane * 8);
        int cc = st * 4 + ck;
        int phys = (cc & 48) | ((cc & 15) ^ ll);
        bf16x8 a0 = *(const bf16x8*)(lds + ll * 1024 + (phys << 4));
        bf16x8 a1 = *(const bf16x8*)(lds + (16 + ll) * 1024 + (phys << 4));
        acc0 = __builtin_amdgcn_mfma_f32_16x16x32_bf16(a0, b, acc0, 0, 0, 0);
        acc1 = __builtin_amdgcn_mfma_f32_16x16x32_bf16(a1, b, acc1, 0, 0, 0);
    }

    // ---------- epilogue ----------
    int colb = w * 16 + ll;
    float bb0 = biasb[colb], bb1 = biasb[D + colb], bb2 = biasb[2 * D + colb], bs4 = biasb[3 * D + colb];
    const float kInvSqrt2 = 0.70710678118654752440f;
#pragma unroll
    for (int fr = 0; fr < 2; ++fr) {
        f32x4 A = fr ? acc1 : acc0;
#pragma unroll
        for (int reg = 0; reg < 4; ++reg) {
            int lr = fr * 16 + ck * 4 + reg;
            long row = (long)row0 + lr;
            if (row >= nN) continue;
            float s0 = sL[lr * NT + 0];
            float s1 = sL[lr * NT + 1];
            float s2 = sL[lr * NT + 2];
            float v = A[reg] + bs4 + s0 * bb0 + s1 * bb1 + s2 * bb2;
            v = 0.5f * v * (1.f + erff(v * kInvSqrt2));
            out[row * D + colb] = v;
        }
    }
}

// ================= FALLBACK PATH (small ws): f32 atomic scatter + f32 GEMM =================
__global__ __launch_bounds__(256) void scatterA_kernel(
    const float* __restrict__ x, const int* __restrict__ ei,
    const int* __restrict__ et, const float* __restrict__ ew,
    float* __restrict__ agg, float* __restrict__ s, int nE) {
    int gtid = blockIdx.x * blockDim.x + threadIdx.x;
    int wave = gtid >> 6;
    int lane = threadIdx.x & 63;
    int nw = (gridDim.x * blockDim.x) >> 6;
    for (int e = wave; e < nE; e += nw) {
        int src = ei[e];
        int dst = ei[nE + e];
        int t = et[e];
        float w = ew[e];
        float2 xv = *(const float2*)(x + (size_t)src * D + lane * 2);
        float* p = agg + (size_t)dst * (NT * D) + t * D + lane * 2;
        unsafeAtomicAdd(p, w * xv.x);
        unsafeAtomicAdd(p + 1, w * xv.y);
        if (lane == 0) unsafeAtomicAdd(s + (size_t)dst * NT + t, w);
    }
}

#define BM 64
#define BK 32
__global__ __launch_bounds__(256) void gemm_gelu_kernel(
    const float* __restrict__ x, const float* __restrict__ agg,
    const float* __restrict__ s, const float* __restrict__ wcat,
    const float* __restrict__ biasb, float* __restrict__ out, int nNodes) {
    __shared__ float As[BK][BM + 1];
    __shared__ float Bs[BK][D];

    int tx = threadIdx.x;
    int row0 = blockIdx.x * BM;
    int cg = tx & 31;
    int rg = tx >> 5;
    int lr = tx >> 3;
    int lc = (tx & 7) * 4;

    float acc[8][4];
#pragma unroll
    for (int i = 0; i < 8; ++i)
#pragma unroll
        for (int j = 0; j < 4; ++j) acc[i][j] = 0.f;

    for (int k0 = 0; k0 < KTOT; k0 += BK) {
        const float* srcBase;
        int strideA, koff;
        if (k0 < D) { srcBase = x; strideA = D; koff = k0; }
        else        { srcBase = agg; strideA = NT * D; koff = k0 - D; }
#pragma unroll
        for (int h = 0; h < 2; ++h) {
            int r = lr + h * 32;
            int node = row0 + r;
            if (node >= nNodes) node = nNodes - 1;
            float4 v = *(const float4*)(srcBase + (size_t)node * strideA + koff + lc);
            As[lc + 0][r] = v.x; As[lc + 1][r] = v.y;
            As[lc + 2][r] = v.z; As[lc + 3][r] = v.w;
        }
        {
            int br = tx >> 5;
            int bc = (tx & 31) * 4;
#pragma unroll
            for (int h = 0; h < 4; ++h) {
                int r = br + h * 8;
                *(float4*)(&Bs[r][bc]) = *(const float4*)(wcat + (size_t)(k0 + r) * D + bc);
            }
        }
        __syncthreads();
#pragma unroll
        for (int kk = 0; kk < BK; ++kk) {
            float4 b = *(const float4*)(&Bs[kk][cg * 4]);
            float a[8];
            *(float4*)(a)     = *(const float4*)(&As[kk][rg * 8]);
            *(float4*)(a + 4) = *(const float4*)(&As[kk][rg * 8 + 4]);
#pragma unroll
            for (int i = 0; i < 8; ++i) {
                acc[i][0] = fmaf(a[i], b.x, acc[i][0]);
                acc[i][1] = fmaf(a[i], b.y, acc[i][1]);
                acc[i][2] = fmaf(a[i], b.z, acc[i][2]);
                acc[i][3] = fmaf(a[i], b.w, acc[i][3]);
            }
        }
        __syncthreads();
    }

    int jc = cg * 4;
    float4 bb0 = *(const float4*)(biasb + 0 * D + jc);
    float4 bb1 = *(const float4*)(biasb + 1 * D + jc);
    float4 bb2 = *(const float4*)(biasb + 2 * D + jc);
    float4 bsv = *(const float4*)(biasb + NT * D + jc);
#pragma unroll
    for (int i = 0; i < 8; ++i) {
        int node = row0 + rg * 8 + i;
        if (node >= nNodes) break;
        float s0 = s[(size_t)node * NT + 0];
        float s1 = s[(size_t)node * NT + 1];
        float s2 = s[(size_t)node * NT + 2];
        float4 r;
        r.x = acc[i][0] + bsv.x + s0 * bb0.x + s1 * bb1.x + s2 * bb2.x;
        r.y = acc[i][1] + bsv.y + s0 * bb0.y + s1 * bb1.y + s2 * bb2.y;
        r.z = acc[i][2] + bsv.z + s0 * bb0.z + s1 * bb1.z + s2 * bb2.z;
        r.w = acc[i][3] + bsv.w + s0 * bb0.w + s1 * bb1.w + s2 * bb2.w;
        const float kInvSqrt2 = 0.70710678118654752440f;
        r.x = 0.5f * r.x * (1.f + erff(r.x * kInvSqrt2));
        r.y = 0.5f * r.y * (1.f + erff(r.y * kInvSqrt2));
        r.z = 0.5f * r.z * (1.f + erff(r.z * kInvSqrt2));
        r.w = 0.5f * r.w * (1.f + erff(r.w * kInvSqrt2));
        *(float4*)(out + (size_t)node * D + jc) = r;
    }
}

// ================= PATH C: zero-workspace fallback =================
__global__ __launch_bounds__(256) void selfmv_kernel(
    const float* __restrict__ x, const float* __restrict__ Ws,
    const float* __restrict__ bs, const float* __restrict__ attn,
    float* __restrict__ out, int nN) {
    float a0 = attn[0], a1 = attn[1], a2 = attn[2], a3 = attn[3];
    float m = fmaxf(fmaxf(a0, a1), fmaxf(a2, a3));
    float e3 = expf(a3 - m);
    float inv = 1.f / (expf(a0 - m) + expf(a1 - m) + expf(a2 - m) + e3);
    float at3 = e3 * inv;
    int wave = (blockIdx.x * blockDim.x + threadIdx.x) >> 6;
    int lane = threadIdx.x & 63;
    int nw = (gridDim.x * blockDim.x) >> 6;
    for (int n = wave; n < nN; n += nw) {
        float2 xr = *(const float2*)(x + (size_t)n * D + lane * 2);
        float acc0 = 0.f, acc1 = 0.f;
#pragma unroll
        for (int k = 0; k < D; ++k) {
            float xv = __shfl((k & 1) ? xr.y : xr.x, k >> 1);
            float2 wv = *(const float2*)(Ws + (size_t)k * D + lane * 2);
            acc0 = fmaf(xv, wv.x, acc0);
            acc1 = fmaf(xv, wv.y, acc1);
        }
        float2 r;
        r.x = at3 * (acc0 + bs[lane * 2]);
        r.y = at3 * (acc1 + bs[lane * 2 + 1]);
        *(float2*)(out + (size_t)n * D + lane * 2) = r;
    }
}

__global__ __launch_bounds__(256) void edgemv_kernel(
    const float* __restrict__ x, const int* __restrict__ ei,
    const int* __restrict__ et, const float* __restrict__ ew,
    const float* __restrict__ We, const float* __restrict__ be,
    const float* __restrict__ attn, float* __restrict__ out, int nE) {
    float a0 = attn[0], a1 = attn[1], a2 = attn[2], a3 = attn[3];
    float m = fmaxf(fmaxf(a0, a1), fmaxf(a2, a3));
    float e0 = expf(a0 - m), e1 = expf(a1 - m), e2 = expf(a2 - m), e3 = expf(a3 - m);
    float inv = 1.f / (e0 + e1 + e2 + e3);
    float at[NT] = {e0 * inv, e1 * inv, e2 * inv};
    int wave = (blockIdx.x * blockDim.x + threadIdx.x) >> 6;
    int lane = threadIdx.x & 63;
    int nw = (gridDim.x * blockDim.x) >> 6;
    for (int e = wave; e < nE; e += nw) {
        int src = ei[e];
        int dst = ei[nE + e];
        int t = et[e];
        float sc = ew[e] * at[t];
        const float* W = We + (size_t)t * D * D;
        float2 xr = *(const float2*)(x + (size_t)src * D + lane * 2);
        float acc0 = 0.f, acc1 = 0.f;
#pragma unroll
        for (int k = 0; k < D; ++k) {
            float xv = __shfl((k & 1) ? xr.y : xr.x, k >> 1);
            float2 wv = *(const float2*)(W + (size_t)k * D + lane * 2);
            acc0 = fmaf(xv, wv.x, acc0);
            acc1 = fmaf(xv, wv.y, acc1);
        }
        float* p = out + (size_t)dst * D + lane * 2;
        unsafeAtomicAdd(p,     sc * (acc0 + be[(size_t)t * D + lane * 2]));
        unsafeAtomicAdd(p + 1, sc * (acc1 + be[(size_t)t * D + lane * 2 + 1]));
    }
}

__global__ void gelu_kernel(float* __restrict__ p, long long n4) {
    long long i = (long long)blockIdx.x * blockDim.x + threadIdx.x;
    long long stride = (long long)gridDim.x * blockDim.x;
    const float kInvSqrt2 = 0.70710678118654752440f;
    for (; i < n4; i += stride) {
        float4 r = ((float4*)p)[i];
        r.x = 0.5f * r.x * (1.f + erff(r.x * kInvSqrt2));
        r.y = 0.5f * r.y * (1.f + erff(r.y * kInvSqrt2));
        r.z = 0.5f * r.z * (1.f + erff(r.z * kInvSqrt2));
        r.w = 0.5f * r.w * (1.f + erff(r.w * kInvSqrt2));
        ((float4*)p)[i] = r;
    }
}

extern "C" void kernel_launch(void* const* d_in, const int* in_sizes, int n_in,
                              void* d_out, int out_size, void* d_ws, size_t ws_size,
                              hipStream_t stream) {
    const float* x = (const float*)d_in[0];
    const int* ei = (const int*)d_in[1];      // int64 in reference -> int32 here
    const int* et = (const int*)d_in[2];
    const float* ew = (const float*)d_in[3];
    const float* W_edge = (const float*)d_in[4];
    const float* b_edge = (const float*)d_in[5];
    const float* W_self = (const float*)d_in[6];
    const float* b_self = (const float*)d_in[7];
    const float* attention = (const float*)d_in[8];
    float* out = (float*)d_out;

    const int nN = in_sizes[0] / D;   // 100000
    const int nE = in_sizes[2];       // 600000

    // ---- fused path workspace (16B-aligned sections) ----
    size_t off = 0;
    auto take = [&](size_t bytes) { size_t o = (off + 15) & ~(size_t)15; off = o + bytes; return o; };
    size_t o_wcat  = take((size_t)KTOT * D * 4);
    size_t o_biasb = take((size_t)KTOT * 4);
    size_t o_bfrag = take(131072);
    size_t o_deg   = take(((size_t)nN + 2) * 4);          // deg[nN] (3x10-bit fields) + ovfc
    size_t o_ovfl  = take((size_t)nE * 4);
    size_t o_csr   = take((size_t)nN * NCAP * 8);
    size_t o_xb    = take((size_t)nN * D * 2);
    size_t needFused = off;

    if (ws_size >= needFused && nN < (1 << 20)) {
        char* ws = (char*)d_ws;
        float* wcat = (float*)(ws + o_wcat);
        float* biasb = (float*)(ws + o_biasb);
        unsigned short* bfrag = (unsigned short*)(ws + o_bfrag);
        int* deg = (int*)(ws + o_deg);
        int* ovfc = deg + nN;
        int* ovfl = (int*)(ws + o_ovfl);
        int2* csr = (int2*)(ws + o_csr);
        unsigned short* xb = (unsigned short*)(ws + o_xb);

        hipLaunchKernelGGL(prep_kernel, dim3(64), dim3(256), 0, stream,
                           W_edge, b_edge, W_self, b_self, attention, wcat, biasb, bfrag,
                           deg, nN + 2);
        hipLaunchKernelGGL(xcvt_fill_kernel, dim3((nE + 255) / 256), dim3(256), 0, stream,
                           x, xb, nN, ei, et, ew, deg, csr, ovfc, ovfl, nE);
        hipLaunchKernelGGL(fused_gemm_kernel, dim3((nN + TM - 1) / TM), dim3(512), 0, stream,
                           xb, csr, deg, bfrag, biasb, ei, et, ew, ovfc, ovfl, out, nN, nE);
        return;
    }

    const size_t baseFloats = (size_t)nN * NT * D + (size_t)nN * NT + (size_t)KTOT * D + KTOT;
    if (ws_size >= baseFloats * 4) {
        float* agg = (float*)d_ws;
        float* sW = agg + (size_t)nN * NT * D;
        float* wcat = sW + (size_t)nN * NT;
        float* biasb = wcat + (size_t)KTOT * D;
        long long zeroFloats = (long long)nN * (NT * D + NT);
        hipLaunchKernelGGL(zero_kernel, dim3(2048), dim3(256), 0, stream, agg, (zeroFloats + 3) / 4);
        hipLaunchKernelGGL(prep_kernel, dim3(64), dim3(256), 0, stream,
                           W_edge, b_edge, W_self, b_self, attention, wcat, biasb,
                           (unsigned short*)nullptr, (int*)nullptr, 0);
        hipLaunchKernelGGL(scatterA_kernel, dim3(2048), dim3(256), 0, stream,
                           x, ei, et, ew, agg, sW, nE);
        hipLaunchKernelGGL(gemm_gelu_kernel, dim3((nN + BM - 1) / BM), dim3(256), 0, stream,
                           x, agg, sW, wcat, biasb, out, nN);
    } else {
        hipLaunchKernelGGL(selfmv_kernel, dim3(2048), dim3(256), 0, stream,
                           x, W_self, b_self, attention, out, nN);
        hipLaunchKernelGGL(edgemv_kernel, dim3(2048), dim3(256), 0, stream,
                           x, ei, et, ew, W_edge, b_edge, attention, out, nE);
        hipLaunchKernelGGL(gelu_kernel, dim3(2048), dim3(256), 0, stream,
                           out, (long long)nN * D / 4);
    }
}

// Round 15
// 109.591 us; speedup vs baseline: 1.1252x; 1.0044x over previous
//
#include <hip/hip_runtime.h>
#include <hip/hip_bf16.h>
#include <math.h>

#define D 128
#define NT 3
#define KTOT (D * (NT + 1))   // 512
#define TM 32                 // nodes per fused block
#define TCAP 12               // per-(node,type) csr capacity
#define NCAP (3 * TCAP)       // 36 slots per node

typedef __attribute__((ext_vector_type(8))) __bf16 bf16x8;
typedef __attribute__((ext_vector_type(4))) float f32x4;

__device__ inline unsigned short f2bf(float f) {
    unsigned int u = __float_as_uint(f);
    unsigned int r = (u + 0x7FFFu + ((u >> 16) & 1u)) >> 16;
    return (unsigned short)r;
}
__device__ inline float bf2f(unsigned int low16) {
    return __uint_as_float(low16 << 16);
}
// packed RNE f32x2 -> bf16x2 (v_cvt_pk_bf16_f32)
__device__ inline unsigned int pk2(float a, float b) {
    __hip_bfloat162 h = __float22bfloat162_rn(make_float2(a, b));
    return *(unsigned int*)&h;
}

// ---------------- zero helper (fallback path) ----------------
__global__ void zero_kernel(float* __restrict__ p, long long n4) {
    long long i = (long long)blockIdx.x * blockDim.x + threadIdx.x;
    long long stride = (long long)gridDim.x * blockDim.x;
    float4 z = make_float4(0.f, 0.f, 0.f, 0.f);
    for (; i < n4; i += stride) ((float4*)p)[i] = z;
}

// ---------------- prep: softmax(attention) -> wcat, biasb, bfrag; zero deg/ovfc ----------------
__global__ void prep_kernel(const float* __restrict__ W_edge, const float* __restrict__ b_edge,
                            const float* __restrict__ W_self, const float* __restrict__ b_self,
                            const float* __restrict__ attention,
                            float* __restrict__ wcat, float* __restrict__ biasb,
                            unsigned short* __restrict__ bfrag,
                            int* __restrict__ zeroMe, int zeroN) {
    float a0 = attention[0], a1 = attention[1], a2 = attention[2], a3 = attention[3];
    float m = fmaxf(fmaxf(a0, a1), fmaxf(a2, a3));
    float e0 = expf(a0 - m), e1 = expf(a1 - m), e2 = expf(a2 - m), e3 = expf(a3 - m);
    float inv = 1.f / (e0 + e1 + e2 + e3);
    float at[4] = {e0 * inv, e1 * inv, e2 * inv, e3 * inv};

    int idx0 = blockIdx.x * blockDim.x + threadIdx.x;
    int stride = gridDim.x * blockDim.x;
    if (zeroMe) {
        for (int i = idx0; i < zeroN; i += stride) zeroMe[i] = 0;
    }
    for (int i = idx0; i < KTOT * D; i += stride) {
        int k = i >> 7, j = i & (D - 1);
        float v;
        if (k < D) {
            v = at[NT] * W_self[k * D + j];
        } else {
            int t = (k - D) >> 7;
            int kk = (k - D) & (D - 1);
            v = at[t] * W_edge[(t * D + kk) * D + j];
        }
        wcat[i] = v;
    }
    for (int i = idx0; i < KTOT; i += stride) {
        if (i < NT * D) {
            int t = i >> 7, j = i & (D - 1);
            biasb[i] = at[t] * b_edge[t * D + j];
        } else {
            biasb[i] = at[NT] * b_self[i - NT * D];
        }
    }
    if (bfrag) {
        // bfrag: [(step*8+cf)*64+lane]*8 ; B[k][col], col=cf*16+(l&15), k=step*32+(l>>4)*8+j
        for (int i = idx0; i < 16 * 8 * 64; i += stride) {
            int l = i & 63;
            int cf = (i >> 6) & 7;
            int step = i >> 9;
            int col = cf * 16 + (l & 15);
            int kb = step * 32 + ((l >> 4) * 8);
#pragma unroll
            for (int j = 0; j < 8; ++j) {
                int k = kb + j;
                float v;
                if (k < D) {
                    v = at[NT] * W_self[k * D + col];
                } else {
                    int t = (k - D) >> 7;
                    int kk = (k - D) & (D - 1);
                    v = at[t] * W_edge[(t * D + kk) * D + col];
                }
                bfrag[(size_t)i * 8 + j] = f2bf(v);
            }
        }
    }
}

// ---------------- merged per-thread: edge fill (atomic hidden under xcvt) + x->bf16 ----------------
__global__ __launch_bounds__(256) void xcvt_fill_kernel(
    const float* __restrict__ x, unsigned short* __restrict__ xb, int nN,
    const int* __restrict__ ei, const int* __restrict__ et, const float* __restrict__ ew,
    int* __restrict__ deg, int2* __restrict__ csr, int* __restrict__ ovfcnt,
    int* __restrict__ ovflist, int nE) {
    int e = blockIdx.x * blockDim.x + threadIdx.x;

    // issue edge loads early
    int dst = 0, src = 0, t = 0;
    float w = 0.f;
    bool act = (e < nE);
    if (act) {
        dst = ei[nE + e];
        src = ei[e];
        t = et[e];
        w = ew[e];
    }

    // issue the counter atomic NOW — its latency hides under the xcvt stream
    int pos = 0;
    if (act) {
        int old = atomicAdd(deg + dst, 1 << (10 * t));
        pos = (old >> (10 * t)) & 1023;
    }

    // streaming xcvt (covers edge-load + atomic latency)
    int total = nN * (D / 4);
    int stride = gridDim.x * blockDim.x;
    for (int i = e; i < total; i += stride) {
        int n = i >> 5;
        int c4 = (i & 31) * 4;
        float4 v = *(const float4*)(x + (size_t)n * D + c4);
        uint2 o;
        o.x = pk2(v.x, v.y);
        o.y = pk2(v.z, v.w);
        *(uint2*)(xb + (size_t)n * D + c4) = o;
    }

    // csr write (atomic result long since returned)
    if (act) {
        if (pos < TCAP) {
            csr[(size_t)dst * NCAP + t * TCAP + pos] = make_int2(src, __float_as_int(w));
        } else {
            int o = atomicAdd(ovfcnt, 1);
            ovflist[o] = e;
        }
    }
}

// ---------------- fused gather + MFMA GEMM (quad-unrolled type-segmented gather) ----------------
// Block: 32 nodes, 512 threads (8 waves). LDS: A[32][64 chunks of 16B] (chunk XOR swizzle) @0
// (32KB); s[32][3] f32 @32768. Total 33152 -> 4 blocks/CU (32 waves/CU).
__global__ __launch_bounds__(512, 8) void fused_gemm_kernel(
    const unsigned short* __restrict__ xb, const int2* __restrict__ csr,
    const int* __restrict__ deg, const unsigned short* __restrict__ bfrag,
    const float* __restrict__ biasb,
    const int* __restrict__ ei, const int* __restrict__ et, const float* __restrict__ ew,
    const int* __restrict__ ovfc, const int* __restrict__ ovfl,
    float* __restrict__ out, int nN, int nE) {
    __shared__ unsigned char lds[33152];
    float* sL = (float*)(lds + 32768);
    int t = threadIdx.x;
    int w = t >> 6;
    int lane = t & 63;
    int gl = lane & 15;
    int gbase = lane & 48;
    int row0 = blockIdx.x * TM;

    // ---------- gather phase: wave w owns nodes row0 + w*4 .. +3 (16 lanes/node) ----------
    int lrow = w * 4 + (lane >> 4);
    int node = row0 + lrow;
    int nclamp = (node < nN) ? node : (nN - 1);
    int swz = lrow & 15;
    int dgw = (node < nN) ? deg[nclamp] : 0;
    int cnt0 = dgw & 1023;          cnt0 = cnt0 > TCAP ? TCAP : cnt0;
    int cnt1 = (dgw >> 10) & 1023;  cnt1 = cnt1 > TCAP ? TCAP : cnt1;
    int cnt2 = (dgw >> 20) & 1023;  cnt2 = cnt2 > TCAP ? TCAP : cnt2;

    const int2* c = csr + (size_t)nclamp * NCAP;
    int gli = (gl < TCAP) ? gl : (TCAP - 1);
    int2 m0 = c[gli];
    int2 m1 = c[TCAP + gli];
    int2 m2 = c[2 * TCAP + gli];

    // own x row -> LDS (chunk-XOR swizzled, both sides — rule #21)
    {
        uint4 xo = *(const uint4*)(xb + (size_t)nclamp * D + gl * 8);
        *(uint4*)(lds + lrow * 1024 + ((gl ^ swz) << 4)) = xo;
    }

    float sw0 = 0.f, sw1 = 0.f, sw2 = 0.f;

#define ACCQ(u0, u1, u2, u3, jj0, jj1)                                              \
    aacc[jj0] = fmaf(w0_, __uint_as_float((u0) << 16), aacc[jj0]);                  \
    aacc[jj1] = fmaf(w0_, __uint_as_float((u0) & 0xFFFF0000u), aacc[jj1]);          \
    aacc[jj0] = fmaf(w1_, __uint_as_float((u1) << 16), aacc[jj0]);                  \
    aacc[jj1] = fmaf(w1_, __uint_as_float((u1) & 0xFFFF0000u), aacc[jj1]);          \
    aacc[jj0] = fmaf(w2_, __uint_as_float((u2) << 16), aacc[jj0]);                  \
    aacc[jj1] = fmaf(w2_, __uint_as_float((u2) & 0xFFFF0000u), aacc[jj1]);          \
    aacc[jj0] = fmaf(w3_, __uint_as_float((u3) << 16), aacc[jj0]);                  \
    aacc[jj1] = fmaf(w3_, __uint_as_float((u3) & 0xFFFF0000u), aacc[jj1]);

#define TYPELOOP(mt, cntt, swt, tt) do {                                            \
    float aacc[8];                                                                  \
    _Pragma("unroll") for (int j = 0; j < 8; ++j) aacc[j] = 0.f;                    \
    for (int i = 0; i < cntt; i += 4) {                                             \
        int ex0 = __shfl(mt.x, gbase + i);                                          \
        int ew0 = __shfl(mt.y, gbase + i);                                          \
        int ex1 = __shfl(mt.x, gbase + i + 1);                                      \
        int ew1 = __shfl(mt.y, gbase + i + 1);                                      \
        int ex2 = __shfl(mt.x, gbase + ((i + 2) & 15));                             \
        int ew2 = __shfl(mt.y, gbase + ((i + 2) & 15));                             \
        int ex3 = __shfl(mt.x, gbase + ((i + 3) & 15));                             \
        int ew3 = __shfl(mt.y, gbase + ((i + 3) & 15));                             \
        bool a1 = (i + 1 < cntt), a2 = (i + 2 < cntt), a3 = (i + 3 < cntt);         \
        int s0 = ex0; if ((unsigned)s0 >= (unsigned)nN) s0 = 0;                     \
        int s1 = a1 ? ex1 : 0; if ((unsigned)s1 >= (unsigned)nN) s1 = 0;            \
        int s2 = a2 ? ex2 : 0; if ((unsigned)s2 >= (unsigned)nN) s2 = 0;            \
        int s3 = a3 ? ex3 : 0; if ((unsigned)s3 >= (unsigned)nN) s3 = 0;            \
        float w0_ = __int_as_float(ew0);                                            \
        float w1_ = a1 ? __int_as_float(ew1) : 0.f;                                 \
        float w2_ = a2 ? __int_as_float(ew2) : 0.f;                                 \
        float w3_ = a3 ? __int_as_float(ew3) : 0.f;                                 \
        uint4 q0 = *(const uint4*)(xb + (size_t)s0 * D + gl * 8);                   \
        uint4 q1 = *(const uint4*)(xb + (size_t)s1 * D + gl * 8);                   \
        uint4 q2 = *(const uint4*)(xb + (size_t)s2 * D + gl * 8);                   \
        uint4 q3 = *(const uint4*)(xb + (size_t)s3 * D + gl * 8);                   \
        swt += (w0_ + w1_) + (w2_ + w3_);                                           \
        ACCQ(q0.x, q1.x, q2.x, q3.x, 0, 1)                                          \
        ACCQ(q0.y, q1.y, q2.y, q3.y, 2, 3)                                          \
        ACCQ(q0.z, q1.z, q2.z, q3.z, 4, 5)                                          \
        ACCQ(q0.w, q1.w, q2.w, q3.w, 6, 7)                                          \
    }                                                                               \
    uint4 o;                                                                        \
    o.x = pk2(aacc[0], aacc[1]);                                                    \
    o.y = pk2(aacc[2], aacc[3]);                                                    \
    o.z = pk2(aacc[4], aacc[5]);                                                    \
    o.w = pk2(aacc[6], aacc[7]);                                                    \
    *(uint4*)(lds + lrow * 1024 + 256 + (tt) * 256 + ((gl ^ swz) << 4)) = o;        \
} while (0)

    TYPELOOP(m0, cnt0, sw0, 0);
    TYPELOOP(m1, cnt1, sw1, 1);
    TYPELOOP(m2, cnt2, sw2, 2);
#undef TYPELOOP
#undef ACCQ

    if (gl < 3) {
        float sv = (gl == 0) ? sw0 : ((gl == 1) ? sw1 : sw2);
        sL[lrow * NT + gl] = sv;
    }
    __syncthreads();

    // ---------- overflow patch (cnt == 0 in practice; correct for any data) ----------
    int cnt = *ovfc;
    if (cnt > 0) {
        if (w == 0 && lane < 16) {
            for (int i = 0; i < cnt; ++i) {
                int e = ovfl[i];
                int dst = ei[nE + e];
                if (dst >= row0 && dst < row0 + TM && dst < nN) {
                    int tt = et[e];
                    float wt = ew[e];
                    int src = ei[e];
                    int lr = dst - row0;
                    uint4* p = (uint4*)(lds + lr * 1024 + 256 + tt * 256 + ((lane ^ (lr & 15)) << 4));
                    uint4 cu = *p;
                    uint4 xr = *(const uint4*)(xb + (size_t)src * D + lane * 8);
                    float f0 = bf2f(cu.x & 0xFFFF) + wt * bf2f(xr.x & 0xFFFF);
                    float f1 = bf2f(cu.x >> 16)    + wt * bf2f(xr.x >> 16);
                    float f2 = bf2f(cu.y & 0xFFFF) + wt * bf2f(xr.y & 0xFFFF);
                    float f3 = bf2f(cu.y >> 16)    + wt * bf2f(xr.y >> 16);
                    float f4 = bf2f(cu.z & 0xFFFF) + wt * bf2f(xr.z & 0xFFFF);
                    float f5 = bf2f(cu.z >> 16)    + wt * bf2f(xr.z >> 16);
                    float f6 = bf2f(cu.w & 0xFFFF) + wt * bf2f(xr.w & 0xFFFF);
                    float f7 = bf2f(cu.w >> 16)    + wt * bf2f(xr.w >> 16);
                    cu.x = pk2(f0, f1);
                    cu.y = pk2(f2, f3);
                    cu.z = pk2(f4, f5);
                    cu.w = pk2(f6, f7);
                    *p = cu;
                    if (lane == 0) sL[lr * NT + tt] += wt;
                }
            }
        }
        __syncthreads();
    }

    // ---------- GEMM phase: 16 K-steps, wave w -> cols w*16..+15, NO barriers ----------
    int ll = lane & 15;
    int ck = lane >> 4;
    f32x4 acc0 = (f32x4){0.f, 0.f, 0.f, 0.f};
    f32x4 acc1 = (f32x4){0.f, 0.f, 0.f, 0.f};
#pragma unroll 4
    for (int st = 0; st < 16; ++st) {
        bf16x8 b = *(const bf16x8*)(bfrag + (size_t)st * 4096 + w * 512 + lane * 8);
        int cc = st * 4 + ck;
        int phys = (cc & 48) | ((cc & 15) ^ ll);
        bf16x8 a0 = *(const bf16x8*)(lds + ll * 1024 + (phys << 4));
        bf16x8 a1 = *(const bf16x8*)(lds + (16 + ll) * 1024 + (phys << 4));
        acc0 = __builtin_amdgcn_mfma_f32_16x16x32_bf16(a0, b, acc0, 0, 0, 0);
        acc1 = __builtin_amdgcn_mfma_f32_16x16x32_bf16(a1, b, acc1, 0, 0, 0);
    }

    // ---------- epilogue ----------
    int colb = w * 16 + ll;
    float bb0 = biasb[colb], bb1 = biasb[D + colb], bb2 = biasb[2 * D + colb], bs4 = biasb[3 * D + colb];
    const float kInvSqrt2 = 0.70710678118654752440f;
#pragma unroll
    for (int fr = 0; fr < 2; ++fr) {
        f32x4 A = fr ? acc1 : acc0;
#pragma unroll
        for (int reg = 0; reg < 4; ++reg) {
            int lr = fr * 16 + ck * 4 + reg;
            long row = (long)row0 + lr;
            if (row >= nN) continue;
            float s0 = sL[lr * NT + 0];
            float s1 = sL[lr * NT + 1];
            float s2 = sL[lr * NT + 2];
            float v = A[reg] + bs4 + s0 * bb0 + s1 * bb1 + s2 * bb2;
            v = 0.5f * v * (1.f + erff(v * kInvSqrt2));
            out[row * D + colb] = v;
        }
    }
}

// ================= FALLBACK PATH (small ws): f32 atomic scatter + f32 GEMM =================
__global__ __launch_bounds__(256) void scatterA_kernel(
    const float* __restrict__ x, const int* __restrict__ ei,
    const int* __restrict__ et, const float* __restrict__ ew,
    float* __restrict__ agg, float* __restrict__ s, int nE) {
    int gtid = blockIdx.x * blockDim.x + threadIdx.x;
    int wave = gtid >> 6;
    int lane = threadIdx.x & 63;
    int nw = (gridDim.x * blockDim.x) >> 6;
    for (int e = wave; e < nE; e += nw) {
        int src = ei[e];
        int dst = ei[nE + e];
        int t = et[e];
        float w = ew[e];
        float2 xv = *(const float2*)(x + (size_t)src * D + lane * 2);
        float* p = agg + (size_t)dst * (NT * D) + t * D + lane * 2;
        unsafeAtomicAdd(p, w * xv.x);
        unsafeAtomicAdd(p + 1, w * xv.y);
        if (lane == 0) unsafeAtomicAdd(s + (size_t)dst * NT + t, w);
    }
}

#define BM 64
#define BK 32
__global__ __launch_bounds__(256) void gemm_gelu_kernel(
    const float* __restrict__ x, const float* __restrict__ agg,
    const float* __restrict__ s, const float* __restrict__ wcat,
    const float* __restrict__ biasb, float* __restrict__ out, int nNodes) {
    __shared__ float As[BK][BM + 1];
    __shared__ float Bs[BK][D];

    int tx = threadIdx.x;
    int row0 = blockIdx.x * BM;
    int cg = tx & 31;
    int rg = tx >> 5;
    int lr = tx >> 3;
    int lc = (tx & 7) * 4;

    float acc[8][4];
#pragma unroll
    for (int i = 0; i < 8; ++i)
#pragma unroll
        for (int j = 0; j < 4; ++j) acc[i][j] = 0.f;

    for (int k0 = 0; k0 < KTOT; k0 += BK) {
        const float* srcBase;
        int strideA, koff;
        if (k0 < D) { srcBase = x; strideA = D; koff = k0; }
        else        { srcBase = agg; strideA = NT * D; koff = k0 - D; }
#pragma unroll
        for (int h = 0; h < 2; ++h) {
            int r = lr + h * 32;
            int node = row0 + r;
            if (node >= nNodes) node = nNodes - 1;
            float4 v = *(const float4*)(srcBase + (size_t)node * strideA + koff + lc);
            As[lc + 0][r] = v.x; As[lc + 1][r] = v.y;
            As[lc + 2][r] = v.z; As[lc + 3][r] = v.w;
        }
        {
            int br = tx >> 5;
            int bc = (tx & 31) * 4;
#pragma unroll
            for (int h = 0; h < 4; ++h) {
                int r = br + h * 8;
                *(float4*)(&Bs[r][bc]) = *(const float4*)(wcat + (size_t)(k0 + r) * D + bc);
            }
        }
        __syncthreads();
#pragma unroll
        for (int kk = 0; kk < BK; ++kk) {
            float4 b = *(const float4*)(&Bs[kk][cg * 4]);
            float a[8];
            *(float4*)(a)     = *(const float4*)(&As[kk][rg * 8]);
            *(float4*)(a + 4) = *(const float4*)(&As[kk][rg * 8 + 4]);
#pragma unroll
            for (int i = 0; i < 8; ++i) {
                acc[i][0] = fmaf(a[i], b.x, acc[i][0]);
                acc[i][1] = fmaf(a[i], b.y, acc[i][1]);
                acc[i][2] = fmaf(a[i], b.z, acc[i][2]);
                acc[i][3] = fmaf(a[i], b.w, acc[i][3]);
            }
        }
        __syncthreads();
    }

    int jc = cg * 4;
    float4 bb0 = *(const float4*)(biasb + 0 * D + jc);
    float4 bb1 = *(const float4*)(biasb + 1 * D + jc);
    float4 bb2 = *(const float4*)(biasb + 2 * D + jc);
    float4 bsv = *(const float4*)(biasb + NT * D + jc);
#pragma unroll
    for (int i = 0; i < 8; ++i) {
        int node = row0 + rg * 8 + i;
        if (node >= nNodes) break;
        float s0 = s[(size_t)node * NT + 0];
        float s1 = s[(size_t)node * NT + 1];
        float s2 = s[(size_t)node * NT + 2];
        float4 r;
        r.x = acc[i][0] + bsv.x + s0 * bb0.x + s1 * bb1.x + s2 * bb2.x;
        r.y = acc[i][1] + bsv.y + s0 * bb0.y + s1 * bb1.y + s2 * bb2.y;
        r.z = acc[i][2] + bsv.z + s0 * bb0.z + s1 * bb1.z + s2 * bb2.z;
        r.w = acc[i][3] + bsv.w + s0 * bb0.w + s1 * bb1.w + s2 * bb2.w;
        const float kInvSqrt2 = 0.70710678118654752440f;
        r.x = 0.5f * r.x * (1.f + erff(r.x * kInvSqrt2));
        r.y = 0.5f * r.y * (1.f + erff(r.y * kInvSqrt2));
        r.z = 0.5f * r.z * (1.f + erff(r.z * kInvSqrt2));
        r.w = 0.5f * r.w * (1.f + erff(r.w * kInvSqrt2));
        *(float4*)(out + (size_t)node * D + jc) = r;
    }
}

// ================= PATH C: zero-workspace fallback =================
__global__ __launch_bounds__(256) void selfmv_kernel(
    const float* __restrict__ x, const float* __restrict__ Ws,
    const float* __restrict__ bs, const float* __restrict__ attn,
    float* __restrict__ out, int nN) {
    float a0 = attn[0], a1 = attn[1], a2 = attn[2], a3 = attn[3];
    float m = fmaxf(fmaxf(a0, a1), fmaxf(a2, a3));
    float e3 = expf(a3 - m);
    float inv = 1.f / (expf(a0 - m) + expf(a1 - m) + expf(a2 - m) + e3);
    float at3 = e3 * inv;
    int wave = (blockIdx.x * blockDim.x + threadIdx.x) >> 6;
    int lane = threadIdx.x & 63;
    int nw = (gridDim.x * blockDim.x) >> 6;
    for (int n = wave; n < nN; n += nw) {
        float2 xr = *(const float2*)(x + (size_t)n * D + lane * 2);
        float acc0 = 0.f, acc1 = 0.f;
#pragma unroll
        for (int k = 0; k < D; ++k) {
            float xv = __shfl((k & 1) ? xr.y : xr.x, k >> 1);
            float2 wv = *(const float2*)(Ws + (size_t)k * D + lane * 2);
            acc0 = fmaf(xv, wv.x, acc0);
            acc1 = fmaf(xv, wv.y, acc1);
        }
        float2 r;
        r.x = at3 * (acc0 + bs[lane * 2]);
        r.y = at3 * (acc1 + bs[lane * 2 + 1]);
        *(float2*)(out + (size_t)n * D + lane * 2) = r;
    }
}

__global__ __launch_bounds__(256) void edgemv_kernel(
    const float* __restrict__ x, const int* __restrict__ ei,
    const int* __restrict__ et, const float* __restrict__ ew,
    const float* __restrict__ We, const float* __restrict__ be,
    const float* __restrict__ attn, float* __restrict__ out, int nE) {
    float a0 = attn[0], a1 = attn[1], a2 = attn[2], a3 = attn[3];
    float m = fmaxf(fmaxf(a0, a1), fmaxf(a2, a3));
    float e0 = expf(a0 - m), e1 = expf(a1 - m), e2 = expf(a2 - m), e3 = expf(a3 - m);
    float inv = 1.f / (e0 + e1 + e2 + e3);
    float at[NT] = {e0 * inv, e1 * inv, e2 * inv};
    int wave = (blockIdx.x * blockDim.x + threadIdx.x) >> 6;
    int lane = threadIdx.x & 63;
    int nw = (gridDim.x * blockDim.x) >> 6;
    for (int e = wave; e < nE; e += nw) {
        int src = ei[e];
        int dst = ei[nE + e];
        int t = et[e];
        float sc = ew[e] * at[t];
        const float* W = We + (size_t)t * D * D;
        float2 xr = *(const float2*)(x + (size_t)src * D + lane * 2);
        float acc0 = 0.f, acc1 = 0.f;
#pragma unroll
        for (int k = 0; k < D; ++k) {
            float xv = __shfl((k & 1) ? xr.y : xr.x, k >> 1);
            float2 wv = *(const float2*)(W + (size_t)k * D + lane * 2);
            acc0 = fmaf(xv, wv.x, acc0);
            acc1 = fmaf(xv, wv.y, acc1);
        }
        float* p = out + (size_t)dst * D + lane * 2;
        unsafeAtomicAdd(p,     sc * (acc0 + be[(size_t)t * D + lane * 2]));
        unsafeAtomicAdd(p + 1, sc * (acc1 + be[(size_t)t * D + lane * 2 + 1]));
    }
}

__global__ void gelu_kernel(float* __restrict__ p, long long n4) {
    long long i = (long long)blockIdx.x * blockDim.x + threadIdx.x;
    long long stride = (long long)gridDim.x * blockDim.x;
    const float kInvSqrt2 = 0.70710678118654752440f;
    for (; i < n4; i += stride) {
        float4 r = ((float4*)p)[i];
        r.x = 0.5f * r.x * (1.f + erff(r.x * kInvSqrt2));
        r.y = 0.5f * r.y * (1.f + erff(r.y * kInvSqrt2));
        r.z = 0.5f * r.z * (1.f + erff(r.z * kInvSqrt2));
        r.w = 0.5f * r.w * (1.f + erff(r.w * kInvSqrt2));
        ((float4*)p)[i] = r;
    }
}

extern "C" void kernel_launch(void* const* d_in, const int* in_sizes, int n_in,
                              void* d_out, int out_size, void* d_ws, size_t ws_size,
                              hipStream_t stream) {
    const float* x = (const float*)d_in[0];
    const int* ei = (const int*)d_in[1];      // int64 in reference -> int32 here
    const int* et = (const int*)d_in[2];
    const float* ew = (const float*)d_in[3];
    const float* W_edge = (const float*)d_in[4];
    const float* b_edge = (const float*)d_in[5];
    const float* W_self = (const float*)d_in[6];
    const float* b_self = (const float*)d_in[7];
    const float* attention = (const float*)d_in[8];
    float* out = (float*)d_out;

    const int nN = in_sizes[0] / D;   // 100000
    const int nE = in_sizes[2];       // 600000

    // ---- fused path workspace (16B-aligned sections) ----
    size_t off = 0;
    auto take = [&](size_t bytes) { size_t o = (off + 15) & ~(size_t)15; off = o + bytes; return o; };
    size_t o_wcat  = take((size_t)KTOT * D * 4);
    size_t o_biasb = take((size_t)KTOT * 4);
    size_t o_bfrag = take(131072);
    size_t o_deg   = take(((size_t)nN + 2) * 4);          // deg[nN] (3x10-bit fields) + ovfc
    size_t o_ovfl  = take((size_t)nE * 4);
    size_t o_csr   = take((size_t)nN * NCAP * 8);
    size_t o_xb    = take((size_t)nN * D * 2);
    size_t needFused = off;

    if (ws_size >= needFused && nN < (1 << 20)) {
        char* ws = (char*)d_ws;
        float* wcat = (float*)(ws + o_wcat);
        float* biasb = (float*)(ws + o_biasb);
        unsigned short* bfrag = (unsigned short*)(ws + o_bfrag);
        int* deg = (int*)(ws + o_deg);
        int* ovfc = deg + nN;
        int* ovfl = (int*)(ws + o_ovfl);
        int2* csr = (int2*)(ws + o_csr);
        unsigned short* xb = (unsigned short*)(ws + o_xb);

        hipLaunchKernelGGL(prep_kernel, dim3(64), dim3(256), 0, stream,
                           W_edge, b_edge, W_self, b_self, attention, wcat, biasb, bfrag,
                           deg, nN + 2);
        hipLaunchKernelGGL(xcvt_fill_kernel, dim3((nE + 255) / 256), dim3(256), 0, stream,
                           x, xb, nN, ei, et, ew, deg, csr, ovfc, ovfl, nE);
        hipLaunchKernelGGL(fused_gemm_kernel, dim3((nN + TM - 1) / TM), dim3(512), 0, stream,
                           xb, csr, deg, bfrag, biasb, ei, et, ew, ovfc, ovfl, out, nN, nE);
        return;
    }

    const size_t baseFloats = (size_t)nN * NT * D + (size_t)nN * NT + (size_t)KTOT * D + KTOT;
    if (ws_size >= baseFloats * 4) {
        float* agg = (float*)d_ws;
        float* sW = agg + (size_t)nN * NT * D;
        float* wcat = sW + (size_t)nN * NT;
        float* biasb = wcat + (size_t)KTOT * D;
        long long zeroFloats = (long long)nN * (NT * D + NT);
        hipLaunchKernelGGL(zero_kernel, dim3(2048), dim3(256), 0, stream, agg, (zeroFloats + 3) / 4);
        hipLaunchKernelGGL(prep_kernel, dim3(64), dim3(256), 0, stream,
                           W_edge, b_edge, W_self, b_self, attention, wcat, biasb,
                           (unsigned short*)nullptr, (int*)nullptr, 0);
        hipLaunchKernelGGL(scatterA_kernel, dim3(2048), dim3(256), 0, stream,
                           x, ei, et, ew, agg, sW, nE);
        hipLaunchKernelGGL(gemm_gelu_kernel, dim3((nN + BM - 1) / BM), dim3(256), 0, stream,
                           x, agg, sW, wcat, biasb, out, nN);
    } else {
        hipLaunchKernelGGL(selfmv_kernel, dim3(2048), dim3(256), 0, stream,
                           x, W_self, b_self, attention, out, nN);
        hipLaunchKernelGGL(edgemv_kernel, dim3(2048), dim3(256), 0, stream,
                           x, ei, et, ew, W_edge, b_edge, attention, out, nE);
        hipLaunchKernelGGL(gelu_kernel, dim3(2048), dim3(256), 0, stream,
                           out, (long long)nN * D / 4);
    }
}

// Round 16
// 108.367 us; speedup vs baseline: 1.1379x; 1.0113x over previous
//
#include <hip/hip_runtime.h>
#include <hip/hip_bf16.h>
#include <math.h>

#define D 128
#define NT 3
#define KTOT (D * (NT + 1))   // 512
#define TM 32                 // nodes per fused block
#define TCAP 12               // per-(node,type) csr capacity
#define NCAP (3 * TCAP)       // 36 slots per node

typedef __attribute__((ext_vector_type(8))) __bf16 bf16x8;
typedef __attribute__((ext_vector_type(4))) float f32x4;

__device__ inline unsigned short f2bf(float f) {
    unsigned int u = __float_as_uint(f);
    unsigned int r = (u + 0x7FFFu + ((u >> 16) & 1u)) >> 16;
    return (unsigned short)r;
}
__device__ inline float bf2f(unsigned int low16) {
    return __uint_as_float(low16 << 16);
}
// packed RNE f32x2 -> bf16x2 (v_cvt_pk_bf16_f32)
__device__ inline unsigned int pk2(float a, float b) {
    __hip_bfloat162 h = __float22bfloat162_rn(make_float2(a, b));
    return *(unsigned int*)&h;
}

// ---------------- zero helper (fallback path) ----------------
__global__ void zero_kernel(float* __restrict__ p, long long n4) {
    long long i = (long long)blockIdx.x * blockDim.x + threadIdx.x;
    long long stride = (long long)gridDim.x * blockDim.x;
    float4 z = make_float4(0.f, 0.f, 0.f, 0.f);
    for (; i < n4; i += stride) ((float4*)p)[i] = z;
}

// ---------------- prep: softmax(attention) -> wcat, biasb, bfrag; zero deg/ovfc ----------------
__global__ void prep_kernel(const float* __restrict__ W_edge, const float* __restrict__ b_edge,
                            const float* __restrict__ W_self, const float* __restrict__ b_self,
                            const float* __restrict__ attention,
                            float* __restrict__ wcat, float* __restrict__ biasb,
                            unsigned short* __restrict__ bfrag,
                            int* __restrict__ zeroMe, int zeroN) {
    float a0 = attention[0], a1 = attention[1], a2 = attention[2], a3 = attention[3];
    float m = fmaxf(fmaxf(a0, a1), fmaxf(a2, a3));
    float e0 = expf(a0 - m), e1 = expf(a1 - m), e2 = expf(a2 - m), e3 = expf(a3 - m);
    float inv = 1.f / (e0 + e1 + e2 + e3);
    float at[4] = {e0 * inv, e1 * inv, e2 * inv, e3 * inv};

    int idx0 = blockIdx.x * blockDim.x + threadIdx.x;
    int stride = gridDim.x * blockDim.x;
    if (zeroMe) {
        for (int i = idx0; i < zeroN; i += stride) zeroMe[i] = 0;
    }
    for (int i = idx0; i < KTOT * D; i += stride) {
        int k = i >> 7, j = i & (D - 1);
        float v;
        if (k < D) {
            v = at[NT] * W_self[k * D + j];
        } else {
            int t = (k - D) >> 7;
            int kk = (k - D) & (D - 1);
            v = at[t] * W_edge[(t * D + kk) * D + j];
        }
        wcat[i] = v;
    }
    for (int i = idx0; i < KTOT; i += stride) {
        if (i < NT * D) {
            int t = i >> 7, j = i & (D - 1);
            biasb[i] = at[t] * b_edge[t * D + j];
        } else {
            biasb[i] = at[NT] * b_self[i - NT * D];
        }
    }
    if (bfrag) {
        // bfrag: [(step*8+cf)*64+lane]*8 ; B[k][col], col=cf*16+(l&15), k=step*32+(l>>4)*8+j
        for (int i = idx0; i < 16 * 8 * 64; i += stride) {
            int l = i & 63;
            int cf = (i >> 6) & 7;
            int step = i >> 9;
            int col = cf * 16 + (l & 15);
            int kb = step * 32 + ((l >> 4) * 8);
#pragma unroll
            for (int j = 0; j < 8; ++j) {
                int k = kb + j;
                float v;
                if (k < D) {
                    v = at[NT] * W_self[k * D + col];
                } else {
                    int t = (k - D) >> 7;
                    int kk = (k - D) & (D - 1);
                    v = at[t] * W_edge[(t * D + kk) * D + col];
                }
                bfrag[(size_t)i * 8 + j] = f2bf(v);
            }
        }
    }
}

// ---------------- merged per-thread: edge fill (4B packed csr) + x->bf16 ----------------
// csr entry: src (17b) | wq (15b fixed-point w*32768). Weights outside [0,1) or
// quantizing to >32767 go to the exact overflow path -> correct for any data.
__global__ __launch_bounds__(256) void xcvt_fill_kernel(
    const float* __restrict__ x, unsigned short* __restrict__ xb, int nN,
    const int* __restrict__ ei, const int* __restrict__ et, const float* __restrict__ ew,
    int* __restrict__ deg, int* __restrict__ csr, int* __restrict__ ovfcnt,
    int* __restrict__ ovflist, int nE) {
    int e = blockIdx.x * blockDim.x + threadIdx.x;

    // issue edge loads early
    int dst = 0, src = 0, t = 0;
    float w = 0.f;
    bool act = (e < nE);
    if (act) {
        dst = ei[nE + e];
        src = ei[e];
        t = et[e];
        w = ew[e];
    }

    // issue the counter atomic NOW — its latency hides under the xcvt stream
    int pos = 0;
    if (act) {
        int old = atomicAdd(deg + dst, 1 << (10 * t));
        pos = (old >> (10 * t)) & 1023;
    }

    // streaming xcvt (covers edge-load + atomic latency)
    int total = nN * (D / 4);
    int stride = gridDim.x * blockDim.x;
    for (int i = e; i < total; i += stride) {
        int n = i >> 5;
        int c4 = (i & 31) * 4;
        float4 v = *(const float4*)(x + (size_t)n * D + c4);
        uint2 o;
        o.x = pk2(v.x, v.y);
        o.y = pk2(v.z, v.w);
        *(uint2*)(xb + (size_t)n * D + c4) = o;
    }

    // csr write (atomic result long since returned)
    if (act) {
        int q = (int)(w * 32768.f);
        bool wok = (w >= 0.f) && (q <= 32767);
        if (pos < TCAP && wok) {
            csr[(size_t)dst * NCAP + t * TCAP + pos] = src | (q << 17);
        } else {
            int o = atomicAdd(ovfcnt, 1);
            ovflist[o] = e;
        }
    }
}

// ---------------- fused gather + MFMA GEMM (4B csr, pair-wise type-segmented gather) ----------------
// Block: 32 nodes, 512 threads (8 waves). LDS: A[32][64 chunks of 16B] (chunk XOR swizzle) @0
// (32KB); s[32][3] f32 @32768. Total 33152 -> 4 blocks/CU (32 waves/CU).
__global__ __launch_bounds__(512, 8) void fused_gemm_kernel(
    const unsigned short* __restrict__ xb, const int* __restrict__ csr,
    const int* __restrict__ deg, const unsigned short* __restrict__ bfrag,
    const float* __restrict__ biasb,
    const int* __restrict__ ei, const int* __restrict__ et, const float* __restrict__ ew,
    const int* __restrict__ ovfc, const int* __restrict__ ovfl,
    float* __restrict__ out, int nN, int nE) {
    __shared__ unsigned char lds[33152];
    float* sL = (float*)(lds + 32768);
    int t = threadIdx.x;
    int w = t >> 6;
    int lane = t & 63;
    int gl = lane & 15;
    int gbase = lane & 48;
    int row0 = blockIdx.x * TM;

    // ---------- gather phase: wave w owns nodes row0 + w*4 .. +3 (16 lanes/node) ----------
    int lrow = w * 4 + (lane >> 4);
    int node = row0 + lrow;
    int nclamp = (node < nN) ? node : (nN - 1);
    int swz = lrow & 15;
    int dgw = (node < nN) ? deg[nclamp] : 0;
    int cnt0 = dgw & 1023;          cnt0 = cnt0 > TCAP ? TCAP : cnt0;
    int cnt1 = (dgw >> 10) & 1023;  cnt1 = cnt1 > TCAP ? TCAP : cnt1;
    int cnt2 = (dgw >> 20) & 1023;  cnt2 = cnt2 > TCAP ? TCAP : cnt2;

    const int* c = csr + (size_t)nclamp * NCAP;
    int gli = (gl < TCAP) ? gl : (TCAP - 1);
    int m0 = c[gli];
    int m1 = c[TCAP + gli];
    int m2 = c[2 * TCAP + gli];

    // own x row -> LDS (chunk-XOR swizzled, both sides — rule #21)
    {
        uint4 xo = *(const uint4*)(xb + (size_t)nclamp * D + gl * 8);
        *(uint4*)(lds + lrow * 1024 + ((gl ^ swz) << 4)) = xo;
    }

    float sw0 = 0.f, sw1 = 0.f, sw2 = 0.f;
    const float kInvQ = 1.f / 32768.f;

#define ACCP(uA, uB, jj0, jj1)                                                      \
    aacc[jj0] = fmaf(w0_, __uint_as_float((uA) << 16), aacc[jj0]);                  \
    aacc[jj1] = fmaf(w0_, __uint_as_float((uA) & 0xFFFF0000u), aacc[jj1]);          \
    aacc[jj0] = fmaf(w1_, __uint_as_float((uB) << 16), aacc[jj0]);                  \
    aacc[jj1] = fmaf(w1_, __uint_as_float((uB) & 0xFFFF0000u), aacc[jj1]);

#define TYPELOOP(mt, cntt, swt, tt) do {                                            \
    float aacc[8];                                                                  \
    _Pragma("unroll") for (int j = 0; j < 8; ++j) aacc[j] = 0.f;                    \
    for (int i = 0; i < cntt; i += 2) {                                             \
        int v0 = __shfl(mt, gbase + i);                                             \
        int v1 = __shfl(mt, gbase + i + 1);                                         \
        bool a1 = (i + 1 < cntt);                                                   \
        int s0 = v0 & 0x1FFFF; if (s0 >= nN) s0 = 0;                                \
        int s1 = a1 ? (v1 & 0x1FFFF) : 0; if (s1 >= nN) s1 = 0;                     \
        float w0_ = (float)((unsigned)v0 >> 17) * kInvQ;                            \
        float w1_ = a1 ? (float)((unsigned)v1 >> 17) * kInvQ : 0.f;                 \
        uint4 q0 = *(const uint4*)(xb + (size_t)s0 * D + gl * 8);                   \
        uint4 q1 = *(const uint4*)(xb + (size_t)s1 * D + gl * 8);                   \
        swt += w0_ + w1_;                                                           \
        ACCP(q0.x, q1.x, 0, 1) ACCP(q0.y, q1.y, 2, 3)                               \
        ACCP(q0.z, q1.z, 4, 5) ACCP(q0.w, q1.w, 6, 7)                               \
    }                                                                               \
    uint4 o;                                                                        \
    o.x = pk2(aacc[0], aacc[1]);                                                    \
    o.y = pk2(aacc[2], aacc[3]);                                                    \
    o.z = pk2(aacc[4], aacc[5]);                                                    \
    o.w = pk2(aacc[6], aacc[7]);                                                    \
    *(uint4*)(lds + lrow * 1024 + 256 + (tt) * 256 + ((gl ^ swz) << 4)) = o;        \
} while (0)

    TYPELOOP(m0, cnt0, sw0, 0);
    TYPELOOP(m1, cnt1, sw1, 1);
    TYPELOOP(m2, cnt2, sw2, 2);
#undef TYPELOOP
#undef ACCP

    if (gl < 3) {
        float sv = (gl == 0) ? sw0 : ((gl == 1) ? sw1 : sw2);
        sL[lrow * NT + gl] = sv;
    }
    __syncthreads();

    // ---------- overflow patch (exact weights; empty in practice, correct for any data) ----------
    int cnt = *ovfc;
    if (cnt > 0) {
        if (w == 0 && lane < 16) {
            for (int i = 0; i < cnt; ++i) {
                int e = ovfl[i];
                int dst = ei[nE + e];
                if (dst >= row0 && dst < row0 + TM && dst < nN) {
                    int tt = et[e];
                    float wt = ew[e];
                    int src = ei[e];
                    int lr = dst - row0;
                    uint4* p = (uint4*)(lds + lr * 1024 + 256 + tt * 256 + ((lane ^ (lr & 15)) << 4));
                    uint4 cu = *p;
                    uint4 xr = *(const uint4*)(xb + (size_t)src * D + lane * 8);
                    float f0 = bf2f(cu.x & 0xFFFF) + wt * bf2f(xr.x & 0xFFFF);
                    float f1 = bf2f(cu.x >> 16)    + wt * bf2f(xr.x >> 16);
                    float f2 = bf2f(cu.y & 0xFFFF) + wt * bf2f(xr.y & 0xFFFF);
                    float f3 = bf2f(cu.y >> 16)    + wt * bf2f(xr.y >> 16);
                    float f4 = bf2f(cu.z & 0xFFFF) + wt * bf2f(xr.z & 0xFFFF);
                    float f5 = bf2f(cu.z >> 16)    + wt * bf2f(xr.z >> 16);
                    float f6 = bf2f(cu.w & 0xFFFF) + wt * bf2f(xr.w & 0xFFFF);
                    float f7 = bf2f(cu.w >> 16)    + wt * bf2f(xr.w >> 16);
                    cu.x = pk2(f0, f1);
                    cu.y = pk2(f2, f3);
                    cu.z = pk2(f4, f5);
                    cu.w = pk2(f6, f7);
                    *p = cu;
                    if (lane == 0) sL[lr * NT + tt] += wt;
                }
            }
        }
        __syncthreads();
    }

    // ---------- GEMM phase: 16 K-steps, wave w -> cols w*16..+15, NO barriers ----------
    int ll = lane & 15;
    int ck = lane >> 4;
    f32x4 acc0 = (f32x4){0.f, 0.f, 0.f, 0.f};
    f32x4 acc1 = (f32x4){0.f, 0.f, 0.f, 0.f};
#pragma unroll 4
    for (int st = 0; st < 16; ++st) {
        bf16x8 b = *(const bf16x8*)(bfrag + (size_t)st * 4096 + w * 512 + lane * 8);
        int cc = st * 4 + ck;
        int phys = (cc & 48) | ((cc & 15) ^ ll);
        bf16x8 a0 = *(const bf16x8*)(lds + ll * 1024 + (phys << 4));
        bf16x8 a1 = *(const bf16x8*)(lds + (16 + ll) * 1024 + (phys << 4));
        acc0 = __builtin_amdgcn_mfma_f32_16x16x32_bf16(a0, b, acc0, 0, 0, 0);
        acc1 = __builtin_amdgcn_mfma_f32_16x16x32_bf16(a1, b, acc1, 0, 0, 0);
    }

    // ---------- epilogue ----------
    int colb = w * 16 + ll;
    float bb0 = biasb[colb], bb1 = biasb[D + colb], bb2 = biasb[2 * D + colb], bs4 = biasb[3 * D + colb];
    const float kInvSqrt2 = 0.70710678118654752440f;
#pragma unroll
    for (int fr = 0; fr < 2; ++fr) {
        f32x4 A = fr ? acc1 : acc0;
#pragma unroll
        for (int reg = 0; reg < 4; ++reg) {
            int lr = fr * 16 + ck * 4 + reg;
            long row = (long)row0 + lr;
            if (row >= nN) continue;
            float s0 = sL[lr * NT + 0];
            float s1 = sL[lr * NT + 1];
            float s2 = sL[lr * NT + 2];
            float v = A[reg] + bs4 + s0 * bb0 + s1 * bb1 + s2 * bb2;
            v = 0.5f * v * (1.f + erff(v * kInvSqrt2));
            out[row * D + colb] = v;
        }
    }
}

// ================= FALLBACK PATH (small ws): f32 atomic scatter + f32 GEMM =================
__global__ __launch_bounds__(256) void scatterA_kernel(
    const float* __restrict__ x, const int* __restrict__ ei,
    const int* __restrict__ et, const float* __restrict__ ew,
    float* __restrict__ agg, float* __restrict__ s, int nE) {
    int gtid = blockIdx.x * blockDim.x + threadIdx.x;
    int wave = gtid >> 6;
    int lane = threadIdx.x & 63;
    int nw = (gridDim.x * blockDim.x) >> 6;
    for (int e = wave; e < nE; e += nw) {
        int src = ei[e];
        int dst = ei[nE + e];
        int t = et[e];
        float w = ew[e];
        float2 xv = *(const float2*)(x + (size_t)src * D + lane * 2);
        float* p = agg + (size_t)dst * (NT * D) + t * D + lane * 2;
        unsafeAtomicAdd(p, w * xv.x);
        unsafeAtomicAdd(p + 1, w * xv.y);
        if (lane == 0) unsafeAtomicAdd(s + (size_t)dst * NT + t, w);
    }
}

#define BM 64
#define BK 32
__global__ __launch_bounds__(256) void gemm_gelu_kernel(
    const float* __restrict__ x, const float* __restrict__ agg,
    const float* __restrict__ s, const float* __restrict__ wcat,
    const float* __restrict__ biasb, float* __restrict__ out, int nNodes) {
    __shared__ float As[BK][BM + 1];
    __shared__ float Bs[BK][D];

    int tx = threadIdx.x;
    int row0 = blockIdx.x * BM;
    int cg = tx & 31;
    int rg = tx >> 5;
    int lr = tx >> 3;
    int lc = (tx & 7) * 4;

    float acc[8][4];
#pragma unroll
    for (int i = 0; i < 8; ++i)
#pragma unroll
        for (int j = 0; j < 4; ++j) acc[i][j] = 0.f;

    for (int k0 = 0; k0 < KTOT; k0 += BK) {
        const float* srcBase;
        int strideA, koff;
        if (k0 < D) { srcBase = x; strideA = D; koff = k0; }
        else        { srcBase = agg; strideA = NT * D; koff = k0 - D; }
#pragma unroll
        for (int h = 0; h < 2; ++h) {
            int r = lr + h * 32;
            int node = row0 + r;
            if (node >= nNodes) node = nNodes - 1;
            float4 v = *(const float4*)(srcBase + (size_t)node * strideA + koff + lc);
            As[lc + 0][r] = v.x; As[lc + 1][r] = v.y;
            As[lc + 2][r] = v.z; As[lc + 3][r] = v.w;
        }
        {
            int br = tx >> 5;
            int bc = (tx & 31) * 4;
#pragma unroll
            for (int h = 0; h < 4; ++h) {
                int r = br + h * 8;
                *(float4*)(&Bs[r][bc]) = *(const float4*)(wcat + (size_t)(k0 + r) * D + bc);
            }
        }
        __syncthreads();
#pragma unroll
        for (int kk = 0; kk < BK; ++kk) {
            float4 b = *(const float4*)(&Bs[kk][cg * 4]);
            float a[8];
            *(float4*)(a)     = *(const float4*)(&As[kk][rg * 8]);
            *(float4*)(a + 4) = *(const float4*)(&As[kk][rg * 8 + 4]);
#pragma unroll
            for (int i = 0; i < 8; ++i) {
                acc[i][0] = fmaf(a[i], b.x, acc[i][0]);
                acc[i][1] = fmaf(a[i], b.y, acc[i][1]);
                acc[i][2] = fmaf(a[i], b.z, acc[i][2]);
                acc[i][3] = fmaf(a[i], b.w, acc[i][3]);
            }
        }
        __syncthreads();
    }

    int jc = cg * 4;
    float4 bb0 = *(const float4*)(biasb + 0 * D + jc);
    float4 bb1 = *(const float4*)(biasb + 1 * D + jc);
    float4 bb2 = *(const float4*)(biasb + 2 * D + jc);
    float4 bsv = *(const float4*)(biasb + NT * D + jc);
#pragma unroll
    for (int i = 0; i < 8; ++i) {
        int node = row0 + rg * 8 + i;
        if (node >= nNodes) break;
        float s0 = s[(size_t)node * NT + 0];
        float s1 = s[(size_t)node * NT + 1];
        float s2 = s[(size_t)node * NT + 2];
        float4 r;
        r.x = acc[i][0] + bsv.x + s0 * bb0.x + s1 * bb1.x + s2 * bb2.x;
        r.y = acc[i][1] + bsv.y + s0 * bb0.y + s1 * bb1.y + s2 * bb2.y;
        r.z = acc[i][2] + bsv.z + s0 * bb0.z + s1 * bb1.z + s2 * bb2.z;
        r.w = acc[i][3] + bsv.w + s0 * bb0.w + s1 * bb1.w + s2 * bb2.w;
        const float kInvSqrt2 = 0.70710678118654752440f;
        r.x = 0.5f * r.x * (1.f + erff(r.x * kInvSqrt2));
        r.y = 0.5f * r.y * (1.f + erff(r.y * kInvSqrt2));
        r.z = 0.5f * r.z * (1.f + erff(r.z * kInvSqrt2));
        r.w = 0.5f * r.w * (1.f + erff(r.w * kInvSqrt2));
        *(float4*)(out + (size_t)node * D + jc) = r;
    }
}

// ================= PATH C: zero-workspace fallback =================
__global__ __launch_bounds__(256) void selfmv_kernel(
    const float* __restrict__ x, const float* __restrict__ Ws,
    const float* __restrict__ bs, const float* __restrict__ attn,
    float* __restrict__ out, int nN) {
    float a0 = attn[0], a1 = attn[1], a2 = attn[2], a3 = attn[3];
    float m = fmaxf(fmaxf(a0, a1), fmaxf(a2, a3));
    float e3 = expf(a3 - m);
    float inv = 1.f / (expf(a0 - m) + expf(a1 - m) + expf(a2 - m) + e3);
    float at3 = e3 * inv;
    int wave = (blockIdx.x * blockDim.x + threadIdx.x) >> 6;
    int lane = threadIdx.x & 63;
    int nw = (gridDim.x * blockDim.x) >> 6;
    for (int n = wave; n < nN; n += nw) {
        float2 xr = *(const float2*)(x + (size_t)n * D + lane * 2);
        float acc0 = 0.f, acc1 = 0.f;
#pragma unroll
        for (int k = 0; k < D; ++k) {
            float xv = __shfl((k & 1) ? xr.y : xr.x, k >> 1);
            float2 wv = *(const float2*)(Ws + (size_t)k * D + lane * 2);
            acc0 = fmaf(xv, wv.x, acc0);
            acc1 = fmaf(xv, wv.y, acc1);
        }
        float2 r;
        r.x = at3 * (acc0 + bs[lane * 2]);
        r.y = at3 * (acc1 + bs[lane * 2 + 1]);
        *(float2*)(out + (size_t)n * D + lane * 2) = r;
    }
}

__global__ __launch_bounds__(256) void edgemv_kernel(
    const float* __restrict__ x, const int* __restrict__ ei,
    const int* __restrict__ et, const float* __restrict__ ew,
    const float* __restrict__ We, const float* __restrict__ be,
    const float* __restrict__ attn, float* __restrict__ out, int nE) {
    float a0 = attn[0], a1 = attn[1], a2 = attn[2], a3 = attn[3];
    float m = fmaxf(fmaxf(a0, a1), fmaxf(a2, a3));
    float e0 = expf(a0 - m), e1 = expf(a1 - m), e2 = expf(a2 - m), e3 = expf(a3 - m);
    float inv = 1.f / (e0 + e1 + e2 + e3);
    float at[NT] = {e0 * inv, e1 * inv, e2 * inv};
    int wave = (blockIdx.x * blockDim.x + threadIdx.x) >> 6;
    int lane = threadIdx.x & 63;
    int nw = (gridDim.x * blockDim.x) >> 6;
    for (int e = wave; e < nE; e += nw) {
        int src = ei[e];
        int dst = ei[nE + e];
        int t = et[e];
        float sc = ew[e] * at[t];
        const float* W = We + (size_t)t * D * D;
        float2 xr = *(const float2*)(x + (size_t)src * D + lane * 2);
        float acc0 = 0.f, acc1 = 0.f;
#pragma unroll
        for (int k = 0; k < D; ++k) {
            float xv = __shfl((k & 1) ? xr.y : xr.x, k >> 1);
            float2 wv = *(const float2*)(W + (size_t)k * D + lane * 2);
            acc0 = fmaf(xv, wv.x, acc0);
            acc1 = fmaf(xv, wv.y, acc1);
        }
        float* p = out + (size_t)dst * D + lane * 2;
        unsafeAtomicAdd(p,     sc * (acc0 + be[(size_t)t * D + lane * 2]));
        unsafeAtomicAdd(p + 1, sc * (acc1 + be[(size_t)t * D + lane * 2 + 1]));
    }
}

__global__ void gelu_kernel(float* __restrict__ p, long long n4) {
    long long i = (long long)blockIdx.x * blockDim.x + threadIdx.x;
    long long stride = (long long)gridDim.x * blockDim.x;
    const float kInvSqrt2 = 0.70710678118654752440f;
    for (; i < n4; i += stride) {
        float4 r = ((float4*)p)[i];
        r.x = 0.5f * r.x * (1.f + erff(r.x * kInvSqrt2));
        r.y = 0.5f * r.y * (1.f + erff(r.y * kInvSqrt2));
        r.z = 0.5f * r.z * (1.f + erff(r.z * kInvSqrt2));
        r.w = 0.5f * r.w * (1.f + erff(r.w * kInvSqrt2));
        ((float4*)p)[i] = r;
    }
}

extern "C" void kernel_launch(void* const* d_in, const int* in_sizes, int n_in,
                              void* d_out, int out_size, void* d_ws, size_t ws_size,
                              hipStream_t stream) {
    const float* x = (const float*)d_in[0];
    const int* ei = (const int*)d_in[1];      // int64 in reference -> int32 here
    const int* et = (const int*)d_in[2];
    const float* ew = (const float*)d_in[3];
    const float* W_edge = (const float*)d_in[4];
    const float* b_edge = (const float*)d_in[5];
    const float* W_self = (const float*)d_in[6];
    const float* b_self = (const float*)d_in[7];
    const float* attention = (const float*)d_in[8];
    float* out = (float*)d_out;

    const int nN = in_sizes[0] / D;   // 100000
    const int nE = in_sizes[2];       // 600000

    // ---- fused path workspace (16B-aligned sections) ----
    size_t off = 0;
    auto take = [&](size_t bytes) { size_t o = (off + 15) & ~(size_t)15; off = o + bytes; return o; };
    size_t o_wcat  = take((size_t)KTOT * D * 4);
    size_t o_biasb = take((size_t)KTOT * 4);
    size_t o_bfrag = take(131072);
    size_t o_deg   = take(((size_t)nN + 2) * 4);          // deg[nN] (3x10-bit fields) + ovfc
    size_t o_ovfl  = take((size_t)nE * 4);
    size_t o_csr   = take((size_t)nN * NCAP * 4);         // 4B packed entries
    size_t o_xb    = take((size_t)nN * D * 2);
    size_t needFused = off;

    if (ws_size >= needFused && nN < (1 << 17)) {
        char* ws = (char*)d_ws;
        float* wcat = (float*)(ws + o_wcat);
        float* biasb = (float*)(ws + o_biasb);
        unsigned short* bfrag = (unsigned short*)(ws + o_bfrag);
        int* deg = (int*)(ws + o_deg);
        int* ovfc = deg + nN;
        int* ovfl = (int*)(ws + o_ovfl);
        int* csr = (int*)(ws + o_csr);
        unsigned short* xb = (unsigned short*)(ws + o_xb);

        hipLaunchKernelGGL(prep_kernel, dim3(64), dim3(256), 0, stream,
                           W_edge, b_edge, W_self, b_self, attention, wcat, biasb, bfrag,
                           deg, nN + 2);
        hipLaunchKernelGGL(xcvt_fill_kernel, dim3((nE + 255) / 256), dim3(256), 0, stream,
                           x, xb, nN, ei, et, ew, deg, csr, ovfc, ovfl, nE);
        hipLaunchKernelGGL(fused_gemm_kernel, dim3((nN + TM - 1) / TM), dim3(512), 0, stream,
                           xb, csr, deg, bfrag, biasb, ei, et, ew, ovfc, ovfl, out, nN, nE);
        return;
    }

    const size_t baseFloats = (size_t)nN * NT * D + (size_t)nN * NT + (size_t)KTOT * D + KTOT;
    if (ws_size >= baseFloats * 4) {
        float* agg = (float*)d_ws;
        float* sW = agg + (size_t)nN * NT * D;
        float* wcat = sW + (size_t)nN * NT;
        float* biasb = wcat + (size_t)KTOT * D;
        long long zeroFloats = (long long)nN * (NT * D + NT);
        hipLaunchKernelGGL(zero_kernel, dim3(2048), dim3(256), 0, stream, agg, (zeroFloats + 3) / 4);
        hipLaunchKernelGGL(prep_kernel, dim3(64), dim3(256), 0, stream,
                           W_edge, b_edge, W_self, b_self, attention, wcat, biasb,
                           (unsigned short*)nullptr, (int*)nullptr, 0);
        hipLaunchKernelGGL(scatterA_kernel, dim3(2048), dim3(256), 0, stream,
                           x, ei, et, ew, agg, sW, nE);
        hipLaunchKernelGGL(gemm_gelu_kernel, dim3((nN + BM - 1) / BM), dim3(256), 0, stream,
                           x, agg, sW, wcat, biasb, out, nN);
    } else {
        hipLaunchKernelGGL(selfmv_kernel, dim3(2048), dim3(256), 0, stream,
                           x, W_self, b_self, attention, out, nN);
        hipLaunchKernelGGL(edgemv_kernel, dim3(2048), dim3(256), 0, stream,
                           x, ei, et, ew, W_edge, b_edge, attention, out, nE);
        hipLaunchKernelGGL(gelu_kernel, dim3(2048), dim3(256), 0, stream,
                           out, (long long)nN * D / 4);
    }
}

// Round 17
// 108.194 us; speedup vs baseline: 1.1397x; 1.0016x over previous
//
#include <hip/hip_runtime.h>
#include <hip/hip_bf16.h>
#include <hip/hip_fp16.h>
#include <math.h>

#define D 128
#define NT 3
#define KTOT (D * (NT + 1))   // 512
#define TM 32                 // nodes per fused block
#define TCAP 12               // per-(node,type) csr capacity
#define NCAP (3 * TCAP)       // 36 slots per node

typedef __attribute__((ext_vector_type(8))) _Float16 f16x8;
typedef __attribute__((ext_vector_type(4))) float f32x4;

__device__ inline unsigned short f2bf(float f) {
    unsigned int u = __float_as_uint(f);
    unsigned int r = (u + 0x7FFFu + ((u >> 16) & 1u)) >> 16;
    return (unsigned short)r;
}

// ---------------- zero helper (fallback path) ----------------
__global__ void zero_kernel(float* __restrict__ p, long long n4) {
    long long i = (long long)blockIdx.x * blockDim.x + threadIdx.x;
    long long stride = (long long)gridDim.x * blockDim.x;
    float4 z = make_float4(0.f, 0.f, 0.f, 0.f);
    for (; i < n4; i += stride) ((float4*)p)[i] = z;
}

// ---------------- prep: softmax(attention) -> wcat, biasb, bfrag(f16); zero deg/ovfc ----------------
__global__ void prep_kernel(const float* __restrict__ W_edge, const float* __restrict__ b_edge,
                            const float* __restrict__ W_self, const float* __restrict__ b_self,
                            const float* __restrict__ attention,
                            float* __restrict__ wcat, float* __restrict__ biasb,
                            unsigned short* __restrict__ bfrag,
                            int* __restrict__ zeroMe, int zeroN) {
    float a0 = attention[0], a1 = attention[1], a2 = attention[2], a3 = attention[3];
    float m = fmaxf(fmaxf(a0, a1), fmaxf(a2, a3));
    float e0 = expf(a0 - m), e1 = expf(a1 - m), e2 = expf(a2 - m), e3 = expf(a3 - m);
    float inv = 1.f / (e0 + e1 + e2 + e3);
    float at[4] = {e0 * inv, e1 * inv, e2 * inv, e3 * inv};

    int idx0 = blockIdx.x * blockDim.x + threadIdx.x;
    int stride = gridDim.x * blockDim.x;
    if (zeroMe) {
        for (int i = idx0; i < zeroN; i += stride) zeroMe[i] = 0;
    }
    for (int i = idx0; i < KTOT * D; i += stride) {
        int k = i >> 7, j = i & (D - 1);
        float v;
        if (k < D) {
            v = at[NT] * W_self[k * D + j];
        } else {
            int t = (k - D) >> 7;
            int kk = (k - D) & (D - 1);
            v = at[t] * W_edge[(t * D + kk) * D + j];
        }
        wcat[i] = v;
    }
    for (int i = idx0; i < KTOT; i += stride) {
        if (i < NT * D) {
            int t = i >> 7, j = i & (D - 1);
            biasb[i] = at[t] * b_edge[t * D + j];
        } else {
            biasb[i] = at[NT] * b_self[i - NT * D];
        }
    }
    if (bfrag) {
        // bfrag (f16): [(step*8+cf)*64+lane]*8 ; B[k][col], col=cf*16+(l&15), k=step*32+(l>>4)*8+j
        for (int i = idx0; i < 16 * 8 * 64; i += stride) {
            int l = i & 63;
            int cf = (i >> 6) & 7;
            int step = i >> 9;
            int col = cf * 16 + (l & 15);
            int kb = step * 32 + ((l >> 4) * 8);
#pragma unroll
            for (int j = 0; j < 8; ++j) {
                int k = kb + j;
                float v;
                if (k < D) {
                    v = at[NT] * W_self[k * D + col];
                } else {
                    int t = (k - D) >> 7;
                    int kk = (k - D) & (D - 1);
                    v = at[t] * W_edge[(t * D + kk) * D + col];
                }
                __half hh = __float2half_rn(v);
                bfrag[(size_t)i * 8 + j] = *(unsigned short*)&hh;
            }
        }
    }
}

// ---------------- merged per-thread: edge fill (4B packed csr) + x->f16 ----------------
// csr entry: src (17b) | wq (15b fixed-point w*32768). Weights outside [0,1) or
// quantizing to >32767 go to the exact overflow path -> correct for any data.
__global__ __launch_bounds__(256) void xcvt_fill_kernel(
    const float* __restrict__ x, unsigned short* __restrict__ xb, int nN,
    const int* __restrict__ ei, const int* __restrict__ et, const float* __restrict__ ew,
    int* __restrict__ deg, int* __restrict__ csr, int* __restrict__ ovfcnt,
    int* __restrict__ ovflist, int nE) {
    int e = blockIdx.x * blockDim.x + threadIdx.x;

    // issue edge loads early
    int dst = 0, src = 0, t = 0;
    float w = 0.f;
    bool act = (e < nE);
    if (act) {
        dst = ei[nE + e];
        src = ei[e];
        t = et[e];
        w = ew[e];
    }

    // issue the counter atomic NOW — its latency hides under the xcvt stream
    int pos = 0;
    if (act) {
        int old = atomicAdd(deg + dst, 1 << (10 * t));
        pos = (old >> (10 * t)) & 1023;
    }

    // streaming x -> f16 (covers edge-load + atomic latency)
    int total = nN * (D / 4);
    int stride = gridDim.x * blockDim.x;
    for (int i = e; i < total; i += stride) {
        int n = i >> 5;
        int c4 = (i & 31) * 4;
        float4 v = *(const float4*)(x + (size_t)n * D + c4);
        __half2 h0 = __float22half2_rn(make_float2(v.x, v.y));
        __half2 h1 = __float22half2_rn(make_float2(v.z, v.w));
        uint2 o;
        o.x = *(unsigned int*)&h0;
        o.y = *(unsigned int*)&h1;
        *(uint2*)(xb + (size_t)n * D + c4) = o;
    }

    // csr write (atomic result long since returned)
    if (act) {
        int q = (int)(w * 32768.f);
        bool wok = (w >= 0.f) && (q <= 32767);
        if (pos < TCAP && wok) {
            csr[(size_t)dst * NCAP + t * TCAP + pos] = src | (q << 17);
        } else {
            int o = atomicAdd(ovfcnt, 1);
            ovflist[o] = e;
        }
    }
}

// ---------------- fused gather (pk_fma_f16) + f16 MFMA GEMM ----------------
// Block: 32 nodes, 512 threads (8 waves). LDS: A[32][64 chunks of 16B] (chunk XOR swizzle) @0
// (32KB); s[32][3] f32 @32768. Total 33152 -> 4 blocks/CU (32 waves/CU).
__global__ __launch_bounds__(512, 8) void fused_gemm_kernel(
    const unsigned short* __restrict__ xb, const int* __restrict__ csr,
    const int* __restrict__ deg, const unsigned short* __restrict__ bfrag,
    const float* __restrict__ biasb,
    const int* __restrict__ ei, const int* __restrict__ et, const float* __restrict__ ew,
    const int* __restrict__ ovfc, const int* __restrict__ ovfl,
    float* __restrict__ out, int nN, int nE) {
    __shared__ unsigned char lds[33152];
    float* sL = (float*)(lds + 32768);
    int t = threadIdx.x;
    int w = t >> 6;
    int lane = t & 63;
    int gl = lane & 15;
    int gbase = lane & 48;
    int row0 = blockIdx.x * TM;

    // ---------- gather phase: wave w owns nodes row0 + w*4 .. +3 (16 lanes/node) ----------
    int lrow = w * 4 + (lane >> 4);
    int node = row0 + lrow;
    int nclamp = (node < nN) ? node : (nN - 1);
    int swz = lrow & 15;
    int dgw = (node < nN) ? deg[nclamp] : 0;
    int cnt0 = dgw & 1023;          cnt0 = cnt0 > TCAP ? TCAP : cnt0;
    int cnt1 = (dgw >> 10) & 1023;  cnt1 = cnt1 > TCAP ? TCAP : cnt1;
    int cnt2 = (dgw >> 20) & 1023;  cnt2 = cnt2 > TCAP ? TCAP : cnt2;

    const int* c = csr + (size_t)nclamp * NCAP;
    int gli = (gl < TCAP) ? gl : (TCAP - 1);
    int m0 = c[gli];
    int m1 = c[TCAP + gli];
    int m2 = c[2 * TCAP + gli];

    // own x row -> LDS (chunk-XOR swizzled, both sides — rule #21); already f16
    {
        uint4 xo = *(const uint4*)(xb + (size_t)nclamp * D + gl * 8);
        *(uint4*)(lds + lrow * 1024 + ((gl ^ swz) << 4)) = xo;
    }

    float sw0 = 0.f, sw1 = 0.f, sw2 = 0.f;
    const float kInvQ = 1.f / 32768.f;

#define TYPELOOP(mt, cntt, swt, tt) do {                                            \
    __half2 ah0 = __float2half2_rn(0.f);                                            \
    __half2 ah1 = __float2half2_rn(0.f);                                            \
    __half2 ah2 = __float2half2_rn(0.f);                                            \
    __half2 ah3 = __float2half2_rn(0.f);                                            \
    for (int i = 0; i < cntt; i += 2) {                                             \
        int v0 = __shfl(mt, gbase + i);                                             \
        int v1 = __shfl(mt, gbase + i + 1);                                         \
        bool a1 = (i + 1 < cntt);                                                   \
        int s0 = v0 & 0x1FFFF; if (s0 >= nN) s0 = 0;                                \
        int s1 = a1 ? (v1 & 0x1FFFF) : 0; if (s1 >= nN) s1 = 0;                     \
        float w0_ = (float)((unsigned)v0 >> 17) * kInvQ;                            \
        float w1_ = a1 ? (float)((unsigned)v1 >> 17) * kInvQ : 0.f;                 \
        __half2 w0h = __float2half2_rn(w0_);                                        \
        __half2 w1h = __float2half2_rn(w1_);                                        \
        uint4 q0 = *(const uint4*)(xb + (size_t)s0 * D + gl * 8);                   \
        uint4 q1 = *(const uint4*)(xb + (size_t)s1 * D + gl * 8);                   \
        swt += w0_ + w1_;                                                           \
        ah0 = __hfma2(w0h, *(const __half2*)&q0.x, ah0);                            \
        ah1 = __hfma2(w0h, *(const __half2*)&q0.y, ah1);                            \
        ah2 = __hfma2(w0h, *(const __half2*)&q0.z, ah2);                            \
        ah3 = __hfma2(w0h, *(const __half2*)&q0.w, ah3);                            \
        ah0 = __hfma2(w1h, *(const __half2*)&q1.x, ah0);                            \
        ah1 = __hfma2(w1h, *(const __half2*)&q1.y, ah1);                            \
        ah2 = __hfma2(w1h, *(const __half2*)&q1.z, ah2);                            \
        ah3 = __hfma2(w1h, *(const __half2*)&q1.w, ah3);                            \
    }                                                                               \
    uint4 o;                                                                        \
    o.x = *(unsigned int*)&ah0;                                                     \
    o.y = *(unsigned int*)&ah1;                                                     \
    o.z = *(unsigned int*)&ah2;                                                     \
    o.w = *(unsigned int*)&ah3;                                                     \
    *(uint4*)(lds + lrow * 1024 + 256 + (tt) * 256 + ((gl ^ swz) << 4)) = o;        \
} while (0)

    TYPELOOP(m0, cnt0, sw0, 0);
    TYPELOOP(m1, cnt1, sw1, 1);
    TYPELOOP(m2, cnt2, sw2, 2);
#undef TYPELOOP

    if (gl < 3) {
        float sv = (gl == 0) ? sw0 : ((gl == 1) ? sw1 : sw2);
        sL[lrow * NT + gl] = sv;
    }
    __syncthreads();

    // ---------- overflow patch (exact weights; empty in practice, correct for any data) ----------
    int cnt = *ovfc;
    if (cnt > 0) {
        if (w == 0 && lane < 16) {
            for (int i = 0; i < cnt; ++i) {
                int e = ovfl[i];
                int dst = ei[nE + e];
                if (dst >= row0 && dst < row0 + TM && dst < nN) {
                    int tt = et[e];
                    float wt = ew[e];
                    int src = ei[e];
                    int lr = dst - row0;
                    uint4* p = (uint4*)(lds + lr * 1024 + 256 + tt * 256 + ((lane ^ (lr & 15)) << 4));
                    uint4 cu = *p;
                    uint4 xr = *(const uint4*)(xb + (size_t)src * D + lane * 8);
#define OVFP(cw, xw)                                                                \
                    {                                                               \
                        float2 f = __half22float2(*(__half2*)&(cw));                \
                        float2 g = __half22float2(*(const __half2*)&(xw));          \
                        f.x += wt * g.x; f.y += wt * g.y;                           \
                        __half2 r = __float22half2_rn(f);                           \
                        cw = *(unsigned int*)&r;                                    \
                    }
                    OVFP(cu.x, xr.x)
                    OVFP(cu.y, xr.y)
                    OVFP(cu.z, xr.z)
                    OVFP(cu.w, xr.w)
#undef OVFP
                    *p = cu;
                    if (lane == 0) sL[lr * NT + tt] += wt;
                }
            }
        }
        __syncthreads();
    }

    // ---------- GEMM phase: 16 K-steps, f16 MFMA, wave w -> cols w*16..+15, NO barriers ----------
    int ll = lane & 15;
    int ck = lane >> 4;
    f32x4 acc0 = (f32x4){0.f, 0.f, 0.f, 0.f};
    f32x4 acc1 = (f32x4){0.f, 0.f, 0.f, 0.f};
#pragma unroll 4
    for (int st = 0; st < 16; ++st) {
        f16x8 b = *(const f16x8*)(bfrag + (size_t)st * 4096 + w * 512 + lane * 8);
        int cc = st * 4 + ck;
        int phys = (cc & 48) | ((cc & 15) ^ ll);
        f16x8 a0 = *(const f16x8*)(lds + ll * 1024 + (phys << 4));
        f16x8 a1 = *(const f16x8*)(lds + (16 + ll) * 1024 + (phys << 4));
        acc0 = __builtin_amdgcn_mfma_f32_16x16x32_f16(a0, b, acc0, 0, 0, 0);
        acc1 = __builtin_amdgcn_mfma_f32_16x16x32_f16(a1, b, acc1, 0, 0, 0);
    }

    // ---------- epilogue ----------
    int colb = w * 16 + ll;
    float bb0 = biasb[colb], bb1 = biasb[D + colb], bb2 = biasb[2 * D + colb], bs4 = biasb[3 * D + colb];
    const float kInvSqrt2 = 0.70710678118654752440f;
#pragma unroll
    for (int fr = 0; fr < 2; ++fr) {
        f32x4 A = fr ? acc1 : acc0;
#pragma unroll
        for (int reg = 0; reg < 4; ++reg) {
            int lr = fr * 16 + ck * 4 + reg;
            long row = (long)row0 + lr;
            if (row >= nN) continue;
            float s0 = sL[lr * NT + 0];
            float s1 = sL[lr * NT + 1];
            float s2 = sL[lr * NT + 2];
            float v = A[reg] + bs4 + s0 * bb0 + s1 * bb1 + s2 * bb2;
            v = 0.5f * v * (1.f + erff(v * kInvSqrt2));
            out[row * D + colb] = v;
        }
    }
}

// ================= FALLBACK PATH (small ws): f32 atomic scatter + f32 GEMM =================
__global__ __launch_bounds__(256) void scatterA_kernel(
    const float* __restrict__ x, const int* __restrict__ ei,
    const int* __restrict__ et, const float* __restrict__ ew,
    float* __restrict__ agg, float* __restrict__ s, int nE) {
    int gtid = blockIdx.x * blockDim.x + threadIdx.x;
    int wave = gtid >> 6;
    int lane = threadIdx.x & 63;
    int nw = (gridDim.x * blockDim.x) >> 6;
    for (int e = wave; e < nE; e += nw) {
        int src = ei[e];
        int dst = ei[nE + e];
        int t = et[e];
        float w = ew[e];
        float2 xv = *(const float2*)(x + (size_t)src * D + lane * 2);
        float* p = agg + (size_t)dst * (NT * D) + t * D + lane * 2;
        unsafeAtomicAdd(p, w * xv.x);
        unsafeAtomicAdd(p + 1, w * xv.y);
        if (lane == 0) unsafeAtomicAdd(s + (size_t)dst * NT + t, w);
    }
}

#define BM 64
#define BK 32
__global__ __launch_bounds__(256) void gemm_gelu_kernel(
    const float* __restrict__ x, const float* __restrict__ agg,
    const float* __restrict__ s, const float* __restrict__ wcat,
    const float* __restrict__ biasb, float* __restrict__ out, int nNodes) {
    __shared__ float As[BK][BM + 1];
    __shared__ float Bs[BK][D];

    int tx = threadIdx.x;
    int row0 = blockIdx.x * BM;
    int cg = tx & 31;
    int rg = tx >> 5;
    int lr = tx >> 3;
    int lc = (tx & 7) * 4;

    float acc[8][4];
#pragma unroll
    for (int i = 0; i < 8; ++i)
#pragma unroll
        for (int j = 0; j < 4; ++j) acc[i][j] = 0.f;

    for (int k0 = 0; k0 < KTOT; k0 += BK) {
        const float* srcBase;
        int strideA, koff;
        if (k0 < D) { srcBase = x; strideA = D; koff = k0; }
        else        { srcBase = agg; strideA = NT * D; koff = k0 - D; }
#pragma unroll
        for (int h = 0; h < 2; ++h) {
            int r = lr + h * 32;
            int node = row0 + r;
            if (node >= nNodes) node = nNodes - 1;
            float4 v = *(const float4*)(srcBase + (size_t)node * strideA + koff + lc);
            As[lc + 0][r] = v.x; As[lc + 1][r] = v.y;
            As[lc + 2][r] = v.z; As[lc + 3][r] = v.w;
        }
        {
            int br = tx >> 5;
            int bc = (tx & 31) * 4;
#pragma unroll
            for (int h = 0; h < 4; ++h) {
                int r = br + h * 8;
                *(float4*)(&Bs[r][bc]) = *(const float4*)(wcat + (size_t)(k0 + r) * D + bc);
            }
        }
        __syncthreads();
#pragma unroll
        for (int kk = 0; kk < BK; ++kk) {
            float4 b = *(const float4*)(&Bs[kk][cg * 4]);
            float a[8];
            *(float4*)(a)     = *(const float4*)(&As[kk][rg * 8]);
            *(float4*)(a + 4) = *(const float4*)(&As[kk][rg * 8 + 4]);
#pragma unroll
            for (int i = 0; i < 8; ++i) {
                acc[i][0] = fmaf(a[i], b.x, acc[i][0]);
                acc[i][1] = fmaf(a[i], b.y, acc[i][1]);
                acc[i][2] = fmaf(a[i], b.z, acc[i][2]);
                acc[i][3] = fmaf(a[i], b.w, acc[i][3]);
            }
        }
        __syncthreads();
    }

    int jc = cg * 4;
    float4 bb0 = *(const float4*)(biasb + 0 * D + jc);
    float4 bb1 = *(const float4*)(biasb + 1 * D + jc);
    float4 bb2 = *(const float4*)(biasb + 2 * D + jc);
    float4 bsv = *(const float4*)(biasb + NT * D + jc);
#pragma unroll
    for (int i = 0; i < 8; ++i) {
        int node = row0 + rg * 8 + i;
        if (node >= nNodes) break;
        float s0 = s[(size_t)node * NT + 0];
        float s1 = s[(size_t)node * NT + 1];
        float s2 = s[(size_t)node * NT + 2];
        float4 r;
        r.x = acc[i][0] + bsv.x + s0 * bb0.x + s1 * bb1.x + s2 * bb2.x;
        r.y = acc[i][1] + bsv.y + s0 * bb0.y + s1 * bb1.y + s2 * bb2.y;
        r.z = acc[i][2] + bsv.z + s0 * bb0.z + s1 * bb1.z + s2 * bb2.z;
        r.w = acc[i][3] + bsv.w + s0 * bb0.w + s1 * bb1.w + s2 * bb2.w;
        const float kInvSqrt2 = 0.70710678118654752440f;
        r.x = 0.5f * r.x * (1.f + erff(r.x * kInvSqrt2));
        r.y = 0.5f * r.y * (1.f + erff(r.y * kInvSqrt2));
        r.z = 0.5f * r.z * (1.f + erff(r.z * kInvSqrt2));
        r.w = 0.5f * r.w * (1.f + erff(r.w * kInvSqrt2));
        *(float4*)(out + (size_t)node * D + jc) = r;
    }
}

// ================= PATH C: zero-workspace fallback =================
__global__ __launch_bounds__(256) void selfmv_kernel(
    const float* __restrict__ x, const float* __restrict__ Ws,
    const float* __restrict__ bs, const float* __restrict__ attn,
    float* __restrict__ out, int nN) {
    float a0 = attn[0], a1 = attn[1], a2 = attn[2], a3 = attn[3];
    float m = fmaxf(fmaxf(a0, a1), fmaxf(a2, a3));
    float e3 = expf(a3 - m);
    float inv = 1.f / (expf(a0 - m) + expf(a1 - m) + expf(a2 - m) + e3);
    float at3 = e3 * inv;
    int wave = (blockIdx.x * blockDim.x + threadIdx.x) >> 6;
    int lane = threadIdx.x & 63;
    int nw = (gridDim.x * blockDim.x) >> 6;
    for (int n = wave; n < nN; n += nw) {
        float2 xr = *(const float2*)(x + (size_t)n * D + lane * 2);
        float acc0 = 0.f, acc1 = 0.f;
#pragma unroll
        for (int k = 0; k < D; ++k) {
            float xv = __shfl((k & 1) ? xr.y : xr.x, k >> 1);
            float2 wv = *(const float2*)(Ws + (size_t)k * D + lane * 2);
            acc0 = fmaf(xv, wv.x, acc0);
            acc1 = fmaf(xv, wv.y, acc1);
        }
        float2 r;
        r.x = at3 * (acc0 + bs[lane * 2]);
        r.y = at3 * (acc1 + bs[lane * 2 + 1]);
        *(float2*)(out + (size_t)n * D + lane * 2) = r;
    }
}

__global__ __launch_bounds__(256) void edgemv_kernel(
    const float* __restrict__ x, const int* __restrict__ ei,
    const int* __restrict__ et, const float* __restrict__ ew,
    const float* __restrict__ We, const float* __restrict__ be,
    const float* __restrict__ attn, float* __restrict__ out, int nE) {
    float a0 = attn[0], a1 = attn[1], a2 = attn[2], a3 = attn[3];
    float m = fmaxf(fmaxf(a0, a1), fmaxf(a2, a3));
    float e0 = expf(a0 - m), e1 = expf(a1 - m), e2 = expf(a2 - m), e3 = expf(a3 - m);
    float inv = 1.f / (e0 + e1 + e2 + e3);
    float at[NT] = {e0 * inv, e1 * inv, e2 * inv};
    int wave = (blockIdx.x * blockDim.x + threadIdx.x) >> 6;
    int lane = threadIdx.x & 63;
    int nw = (gridDim.x * blockDim.x) >> 6;
    for (int e = wave; e < nE; e += nw) {
        int src = ei[e];
        int dst = ei[nE + e];
        int t = et[e];
        float sc = ew[e] * at[t];
        const float* W = We + (size_t)t * D * D;
        float2 xr = *(const float2*)(x + (size_t)src * D + lane * 2);
        float acc0 = 0.f, acc1 = 0.f;
#pragma unroll
        for (int k = 0; k < D; ++k) {
            float xv = __shfl((k & 1) ? xr.y : xr.x, k >> 1);
            float2 wv = *(const float2*)(W + (size_t)k * D + lane * 2);
            acc0 = fmaf(xv, wv.x, acc0);
            acc1 = fmaf(xv, wv.y, acc1);
        }
        float* p = out + (size_t)dst * D + lane * 2;
        unsafeAtomicAdd(p,     sc * (acc0 + be[(size_t)t * D + lane * 2]));
        unsafeAtomicAdd(p + 1, sc * (acc1 + be[(size_t)t * D + lane * 2 + 1]));
    }
}

__global__ void gelu_kernel(float* __restrict__ p, long long n4) {
    long long i = (long long)blockIdx.x * blockDim.x + threadIdx.x;
    long long stride = (long long)gridDim.x * blockDim.x;
    const float kInvSqrt2 = 0.70710678118654752440f;
    for (; i < n4; i += stride) {
        float4 r = ((float4*)p)[i];
        r.x = 0.5f * r.x * (1.f + erff(r.x * kInvSqrt2));
        r.y = 0.5f * r.y * (1.f + erff(r.y * kInvSqrt2));
        r.z = 0.5f * r.z * (1.f + erff(r.z * kInvSqrt2));
        r.w = 0.5f * r.w * (1.f + erff(r.w * kInvSqrt2));
        ((float4*)p)[i] = r;
    }
}

extern "C" void kernel_launch(void* const* d_in, const int* in_sizes, int n_in,
                              void* d_out, int out_size, void* d_ws, size_t ws_size,
                              hipStream_t stream) {
    const float* x = (const float*)d_in[0];
    const int* ei = (const int*)d_in[1];      // int64 in reference -> int32 here
    const int* et = (const int*)d_in[2];
    const float* ew = (const float*)d_in[3];
    const float* W_edge = (const float*)d_in[4];
    const float* b_edge = (const float*)d_in[5];
    const float* W_self = (const float*)d_in[6];
    const float* b_self = (const float*)d_in[7];
    const float* attention = (const float*)d_in[8];
    float* out = (float*)d_out;

    const int nN = in_sizes[0] / D;   // 100000
    const int nE = in_sizes[2];       // 600000

    // ---- fused path workspace (16B-aligned sections) ----
    size_t off = 0;
    auto take = [&](size_t bytes) { size_t o = (off + 15) & ~(size_t)15; off = o + bytes; return o; };
    size_t o_wcat  = take((size_t)KTOT * D * 4);
    size_t o_biasb = take((size_t)KTOT * 4);
    size_t o_bfrag = take(131072);
    size_t o_deg   = take(((size_t)nN + 2) * 4);          // deg[nN] (3x10-bit fields) + ovfc
    size_t o_ovfl  = take((size_t)nE * 4);
    size_t o_csr   = take((size_t)nN * NCAP * 4);         // 4B packed entries
    size_t o_xb    = take((size_t)nN * D * 2);
    size_t needFused = off;

    if (ws_size >= needFused && nN < (1 << 17)) {
        char* ws = (char*)d_ws;
        float* wcat = (float*)(ws + o_wcat);
        float* biasb = (float*)(ws + o_biasb);
        unsigned short* bfrag = (unsigned short*)(ws + o_bfrag);
        int* deg = (int*)(ws + o_deg);
        int* ovfc = deg + nN;
        int* ovfl = (int*)(ws + o_ovfl);
        int* csr = (int*)(ws + o_csr);
        unsigned short* xb = (unsigned short*)(ws + o_xb);

        hipLaunchKernelGGL(prep_kernel, dim3(64), dim3(256), 0, stream,
                           W_edge, b_edge, W_self, b_self, attention, wcat, biasb, bfrag,
                           deg, nN + 2);
        hipLaunchKernelGGL(xcvt_fill_kernel, dim3((nE + 255) / 256), dim3(256), 0, stream,
                           x, xb, nN, ei, et, ew, deg, csr, ovfc, ovfl, nE);
        hipLaunchKernelGGL(fused_gemm_kernel, dim3((nN + TM - 1) / TM), dim3(512), 0, stream,
                           xb, csr, deg, bfrag, biasb, ei, et, ew, ovfc, ovfl, out, nN, nE);
        return;
    }

    const size_t baseFloats = (size_t)nN * NT * D + (size_t)nN * NT + (size_t)KTOT * D + KTOT;
    if (ws_size >= baseFloats * 4) {
        float* agg = (float*)d_ws;
        float* sW = agg + (size_t)nN * NT * D;
        float* wcat = sW + (size_t)nN * NT;
        float* biasb = wcat + (size_t)KTOT * D;
        long long zeroFloats = (long long)nN * (NT * D + NT);
        hipLaunchKernelGGL(zero_kernel, dim3(2048), dim3(256), 0, stream, agg, (zeroFloats + 3) / 4);
        hipLaunchKernelGGL(prep_kernel, dim3(64), dim3(256), 0, stream,
                           W_edge, b_edge, W_self, b_self, attention, wcat, biasb,
                           (unsigned short*)nullptr, (int*)nullptr, 0);
        hipLaunchKernelGGL(scatterA_kernel, dim3(2048), dim3(256), 0, stream,
                           x, ei, et, ew, agg, sW, nE);
        hipLaunchKernelGGL(gemm_gelu_kernel, dim3((nN + BM - 1) / BM), dim3(256), 0, stream,
                           x, agg, sW, wcat, biasb, out, nN);
    } else {
        hipLaunchKernelGGL(selfmv_kernel, dim3(2048), dim3(256), 0, stream,
                           x, W_self, b_self, attention, out, nN);
        hipLaunchKernelGGL(edgemv_kernel, dim3(2048), dim3(256), 0, stream,
                           x, ei, et, ew, W_edge, b_edge, attention, out, nE);
        hipLaunchKernelGGL(gelu_kernel, dim3(2048), dim3(256), 0, stream,
                           out, (long long)nN * D / 4);
    }
}